// Round 1
// baseline (1415.273 us; speedup 1.0000x reference)
//
#include <hip/hip_runtime.h>
#include <hip/hip_bf16.h>

#define N_NODES 100000
#define N_EDGES 1600000

// ---------------- graph preprocessing ----------------

__global__ void k_count(const int* __restrict__ ei, int* __restrict__ deg) {
    int e = blockIdx.x * blockDim.x + threadIdx.x;
    if (e < N_EDGES) atomicAdd(&deg[ei[N_EDGES + e]], 1);
}

__global__ void k_dinv(const int* __restrict__ deg, float* __restrict__ dinv) {
    int i = blockIdx.x * blockDim.x + threadIdx.x;
    if (i < N_NODES) dinv[i] = rsqrtf((float)(deg[i] + 1)); // +1 self loop, always >=1
}

__global__ void k_scan1(const int* __restrict__ deg, int* __restrict__ bsum) {
    __shared__ int sm[256];
    int t = threadIdx.x;
    int idx0 = blockIdx.x * 1024 + t * 4;
    int s = 0;
#pragma unroll
    for (int j = 0; j < 4; ++j) { int idx = idx0 + j; if (idx < N_NODES) s += deg[idx]; }
    sm[t] = s; __syncthreads();
    for (int d = 128; d > 0; d >>= 1) { if (t < d) sm[t] += sm[t + d]; __syncthreads(); }
    if (t == 0) bsum[blockIdx.x] = sm[0];
}

__global__ void k_scan2(int* __restrict__ bsum, int B) {
    __shared__ int sm[128];
    int t = threadIdx.x;
    int v = (t < B) ? bsum[t] : 0;
    sm[t] = v; __syncthreads();
    for (int d = 1; d < 128; d <<= 1) {
        int add = (t >= d) ? sm[t - d] : 0;
        __syncthreads(); sm[t] += add; __syncthreads();
    }
    if (t < B) bsum[t] = sm[t] - v; // exclusive
}

__global__ void k_scan3(const int* __restrict__ deg, const int* __restrict__ bsum,
                        int* __restrict__ basep, int* __restrict__ cursor) {
    __shared__ int sm[256];
    int t = threadIdx.x, b = blockIdx.x;
    int idx0 = b * 1024 + t * 4;
    int v[4]; int s = 0;
#pragma unroll
    for (int j = 0; j < 4; ++j) { int idx = idx0 + j; v[j] = (idx < N_NODES) ? deg[idx] : 0; s += v[j]; }
    sm[t] = s; __syncthreads();
    for (int d = 1; d < 256; d <<= 1) {
        int add = (t >= d) ? sm[t - d] : 0;
        __syncthreads(); sm[t] += add; __syncthreads();
    }
    int run = sm[t] - s + bsum[b];
#pragma unroll
    for (int j = 0; j < 4; ++j) {
        int idx = idx0 + j;
        if (idx < N_NODES) { basep[idx] = run; cursor[idx] = run; run += v[j]; }
    }
}

__global__ void k_scatter(const int* __restrict__ ei, int* __restrict__ cursor, int* __restrict__ col) {
    int e = blockIdx.x * blockDim.x + threadIdx.x;
    if (e < N_EDGES) {
        int s = ei[e], d = ei[N_EDGES + e];
        int pos = atomicAdd(&cursor[d], 1);
        col[pos] = s;
    }
}

// ---------------- f32 GEMM: C[n,DOUT] = A[n,din] @ W[din,DOUT] ----------------

template <int DOUT>
__global__ __launch_bounds__(256) void k_gemm(const float* __restrict__ A, const float* __restrict__ W,
                                              float* __restrict__ C, int din) {
    constexpr int COLV = (DOUT >= 128) ? 4 : 2;
    constexpr int NG = DOUT / (32 * COLV); // 128->1, 256->2, 64->1
    __shared__ float hs[64][36];
    __shared__ float ws[32 * DOUT];
    int tid = threadIdx.x;
    int tx = tid & 31, ty = tid >> 5;
    int row0 = blockIdx.x * 64;
    float acc[8][NG][COLV];
#pragma unroll
    for (int r = 0; r < 8; ++r)
#pragma unroll
        for (int g = 0; g < NG; ++g)
#pragma unroll
            for (int c = 0; c < COLV; ++c) acc[r][g][c] = 0.f;

    for (int k0 = 0; k0 < din; k0 += 32) {
#pragma unroll
        for (int i = 0; i < 2; ++i) {
            int lin = tid + i * 256;       // 0..511
            int r = lin >> 3, kq = lin & 7;
            int gr = row0 + r;
            float4 v = make_float4(0.f, 0.f, 0.f, 0.f);
            if (gr < N_NODES) v = *(const float4*)(A + (size_t)gr * din + k0 + kq * 4);
            hs[r][kq * 4 + 0] = v.x; hs[r][kq * 4 + 1] = v.y;
            hs[r][kq * 4 + 2] = v.z; hs[r][kq * 4 + 3] = v.w;
        }
        constexpr int WV = (32 * DOUT / 4) / 256;
#pragma unroll
        for (int i = 0; i < WV; ++i) {
            int lin = tid + i * 256;
            ((float4*)ws)[lin] = *(const float4*)(W + (size_t)k0 * DOUT + lin * 4);
        }
        __syncthreads();

        for (int kk = 0; kk < 32; kk += 4) {
            float a[8][4];
#pragma unroll
            for (int r = 0; r < 8; ++r) {
                float4 av = *(const float4*)&hs[ty * 8 + r][kk];
                a[r][0] = av.x; a[r][1] = av.y; a[r][2] = av.z; a[r][3] = av.w;
            }
            float bv[4][NG][COLV];
#pragma unroll
            for (int q = 0; q < 4; ++q)
#pragma unroll
                for (int g = 0; g < NG; ++g) {
                    if constexpr (COLV == 4) {
                        float4 b4 = *(const float4*)&ws[(kk + q) * DOUT + g * 128 + tx * 4];
                        bv[q][g][0] = b4.x; bv[q][g][1] = b4.y; bv[q][g][2] = b4.z; bv[q][g][3] = b4.w;
                    } else {
                        float2 b2 = *(const float2*)&ws[(kk + q) * DOUT + tx * 2];
                        bv[q][g][0] = b2.x; bv[q][g][1] = b2.y;
                    }
                }
#pragma unroll
            for (int q = 0; q < 4; ++q)
#pragma unroll
                for (int r = 0; r < 8; ++r)
#pragma unroll
                    for (int g = 0; g < NG; ++g)
#pragma unroll
                        for (int c = 0; c < COLV; ++c)
                            acc[r][g][c] += a[r][q] * bv[q][g][c];
        }
        __syncthreads();
    }

#pragma unroll
    for (int r = 0; r < 8; ++r) {
        int gr = row0 + ty * 8 + r;
        if (gr >= N_NODES) continue;
#pragma unroll
        for (int g = 0; g < NG; ++g) {
            if constexpr (COLV == 4) {
                float4 o;
                o.x = acc[r][g][0]; o.y = acc[r][g][1]; o.z = acc[r][g][2]; o.w = acc[r][g][3];
                *(float4*)(C + (size_t)gr * DOUT + g * 128 + tx * 4) = o;
            } else {
                float2 o;
                o.x = acc[r][g][0]; o.y = acc[r][g][1];
                *(float2*)(C + (size_t)gr * DOUT + tx * 2) = o;
            }
        }
    }
}

// ---------------- aggregation: out = relu(dinv_dst*(sum dinv_src*m[src]) + dinv^2*m[self] + b) ----------------

template <int D>
__global__ __launch_bounds__(256) void k_agg(const float* __restrict__ m, const int* __restrict__ col,
                                             const int* __restrict__ basep, const int* __restrict__ deg,
                                             const float* __restrict__ dinv, const float* __restrict__ bias,
                                             float* __restrict__ out) {
    constexpr int VPL = D / 64;
    int w = (blockIdx.x * 256 + threadIdx.x) >> 6;
    if (w >= N_NODES) return;
    int lane = threadIdx.x & 63;
    int fo = lane * VPL;
    float acc[VPL];
#pragma unroll
    for (int k = 0; k < VPL; ++k) acc[k] = 0.f;
    int start = basep[w], cnt = deg[w];
    int j = 0;
    for (; j + 2 <= cnt; j += 2) {
        int s0 = col[start + j], s1 = col[start + j + 1];
        float c0 = dinv[s0], c1 = dinv[s1];
        const float* r0 = m + (size_t)s0 * D + fo;
        const float* r1 = m + (size_t)s1 * D + fo;
        if constexpr (VPL == 4) {
            float4 v0 = *(const float4*)r0, v1 = *(const float4*)r1;
            acc[0] += c0 * v0.x + c1 * v1.x; acc[1] += c0 * v0.y + c1 * v1.y;
            acc[2] += c0 * v0.z + c1 * v1.z; acc[3] += c0 * v0.w + c1 * v1.w;
        } else if constexpr (VPL == 2) {
            float2 v0 = *(const float2*)r0, v1 = *(const float2*)r1;
            acc[0] += c0 * v0.x + c1 * v1.x; acc[1] += c0 * v0.y + c1 * v1.y;
        } else {
            acc[0] += c0 * r0[0] + c1 * r1[0];
        }
    }
    if (j < cnt) {
        int s0 = col[start + j];
        float c0 = dinv[s0];
        const float* r0 = m + (size_t)s0 * D + fo;
        if constexpr (VPL == 4) {
            float4 v0 = *(const float4*)r0;
            acc[0] += c0 * v0.x; acc[1] += c0 * v0.y; acc[2] += c0 * v0.z; acc[3] += c0 * v0.w;
        } else if constexpr (VPL == 2) {
            float2 v0 = *(const float2*)r0;
            acc[0] += c0 * v0.x; acc[1] += c0 * v0.y;
        } else {
            acc[0] += c0 * r0[0];
        }
    }
    float di = dinv[w];
    const float* rs = m + (size_t)w * D + fo;
    if constexpr (VPL == 4) {
        float4 v0 = *(const float4*)rs;
        acc[0] += di * v0.x; acc[1] += di * v0.y; acc[2] += di * v0.z; acc[3] += di * v0.w;
    } else if constexpr (VPL == 2) {
        float2 v0 = *(const float2*)rs;
        acc[0] += di * v0.x; acc[1] += di * v0.y;
    } else {
        acc[0] += di * rs[0];
    }
    float o[VPL];
#pragma unroll
    for (int k = 0; k < VPL; ++k) o[k] = fmaxf(acc[k] * di + bias[fo + k], 0.f);
    float* dst = out + (size_t)w * D + fo;
    if constexpr (VPL == 4) { *(float4*)dst = make_float4(o[0], o[1], o[2], o[3]); }
    else if constexpr (VPL == 2) { *(float2*)dst = make_float2(o[0], o[1]); }
    else { dst[0] = o[0]; }
}

// ---------------- BatchNorm (training mode, batch stats) ----------------

template <int D>
__global__ void k_bnstats(const float* __restrict__ h, float* __restrict__ sums) {
    int f = threadIdx.x; // blockDim == D
    float s = 0.f, s2 = 0.f;
    for (int r = blockIdx.x; r < N_NODES; r += gridDim.x) {
        float v = h[(size_t)r * D + f];
        s += v; s2 += v * v;
    }
    atomicAdd(&sums[f], s);
    atomicAdd(&sums[256 + f], s2);
}

template <int D>
__global__ void k_bnfin(const float* __restrict__ sums, const float* __restrict__ gamma,
                        const float* __restrict__ beta, float* __restrict__ ss) {
    int f = threadIdx.x; // blockDim == D
    float mean = sums[f] * (1.f / N_NODES);
    float var = sums[256 + f] * (1.f / N_NODES) - mean * mean;
    float inv = rsqrtf(var + 1e-5f);
    float sc = gamma[f] * inv;
    ss[f] = sc;
    ss[256 + f] = beta[f] - mean * sc;
}

template <int D>
__global__ void k_bnapply(const float* __restrict__ h, const float* __restrict__ ss, float* __restrict__ o) {
    constexpr int TOT = N_NODES * D / 4;
    int i = blockIdx.x * blockDim.x + threadIdx.x; // float4 index
    if (i >= TOT) return;
    float4 v = ((const float4*)h)[i];
    int f = (i * 4) & (D - 1);
    v.x = v.x * ss[f + 0] + ss[256 + f + 0];
    v.y = v.y * ss[f + 1] + ss[256 + f + 1];
    v.z = v.z * ss[f + 2] + ss[256 + f + 2];
    v.w = v.w * ss[f + 3] + ss[256 + f + 3];
    ((float4*)o)[i] = v;
}

// ---------------- classifier ----------------

__global__ void k_logits(const float* __restrict__ bn4, const float* __restrict__ Wc,
                         const float* __restrict__ bc, float* __restrict__ out) {
    int i = blockIdx.x * blockDim.x + threadIdx.x;
    if (i >= N_NODES) return;
    float a0 = bc[0], a1 = bc[1];
    const float* r = bn4 + (size_t)i * 64;
#pragma unroll
    for (int f = 0; f < 64; ++f) {
        float v = r[f];
        a0 += v * Wc[2 * f];
        a1 += v * Wc[2 * f + 1];
    }
    out[2 * i] = a0;
    out[2 * i + 1] = a1;
}

// ---------------- launch ----------------

extern "C" void kernel_launch(void* const* d_in, const int* in_sizes, int n_in,
                              void* d_out, int out_size, void* d_ws, size_t ws_size,
                              hipStream_t stream) {
    const float* x  = (const float*)d_in[0];
    const int* ei   = (const int*)d_in[1];
    const float* W1 = (const float*)d_in[2];  const float* b1  = (const float*)d_in[3];
    const float* W2 = (const float*)d_in[4];  const float* b2  = (const float*)d_in[5];
    const float* W3 = (const float*)d_in[6];  const float* b3  = (const float*)d_in[7];
    const float* W4 = (const float*)d_in[8];  const float* b4  = (const float*)d_in[9];
    const float* Wc = (const float*)d_in[10]; const float* bc  = (const float*)d_in[11];
    const float* g1 = (const float*)d_in[12]; const float* be1 = (const float*)d_in[13];
    const float* g2 = (const float*)d_in[14]; const float* be2 = (const float*)d_in[15];
    const float* g3 = (const float*)d_in[16]; const float* be3 = (const float*)d_in[17];
    const float* g4 = (const float*)d_in[18]; const float* be4 = (const float*)d_in[19];

    char* wsb = (char*)d_ws;
    size_t off = 0;
    auto alloc = [&](size_t bytes) -> void* {
        void* p = wsb + off;
        off = (off + bytes + 511) & ~(size_t)511;
        return p;
    };
    int* deg    = (int*)alloc((size_t)N_NODES * 4);
    int* basep  = (int*)alloc((size_t)N_NODES * 4);
    int* cursor = (int*)alloc((size_t)N_NODES * 4);
    float* dinv = (float*)alloc((size_t)N_NODES * 4);
    int* col    = (int*)alloc((size_t)N_EDGES * 4);
    int* bsum   = (int*)alloc(128 * 4);
    float* sums = (float*)alloc(512 * 4);
    float* ss   = (float*)alloc(512 * 4);
    float* big0 = (float*)alloc((size_t)N_NODES * 256 * 4);
    float* big1 = (float*)alloc((size_t)N_NODES * 256 * 4);

    float* outLogits = (float*)d_out;
    float* out4 = outLogits + (size_t)N_NODES * 2;
    float* bn4  = out4 + (size_t)N_NODES * 64;

    hipMemsetAsync(deg, 0, (size_t)N_NODES * 4, stream);
    const int B1 = (N_NODES + 1023) / 1024; // 98
    k_count<<<(N_EDGES + 255) / 256, 256, 0, stream>>>(ei, deg);
    k_dinv<<<(N_NODES + 255) / 256, 256, 0, stream>>>(deg, dinv);
    k_scan1<<<B1, 256, 0, stream>>>(deg, bsum);
    k_scan2<<<1, 128, 0, stream>>>(bsum, B1);
    k_scan3<<<B1, 256, 0, stream>>>(deg, bsum, basep, cursor);
    k_scatter<<<(N_EDGES + 255) / 256, 256, 0, stream>>>(ei, cursor, col);

    const int GB = (N_NODES + 63) / 64;
    const int AB = (N_NODES + 3) / 4;

    // Layer 1: 256 -> 128
    k_gemm<128><<<GB, 256, 0, stream>>>(x, W1, big0, 256);
    k_agg<128><<<AB, 256, 0, stream>>>(big0, col, basep, deg, dinv, b1, big1);
    hipMemsetAsync(sums, 0, 512 * 4, stream);
    k_bnstats<128><<<512, 128, 0, stream>>>(big1, sums);
    k_bnfin<128><<<1, 128, 0, stream>>>(sums, g1, be1, ss);
    k_bnapply<128><<<(N_NODES * 128 / 4 + 255) / 256, 256, 0, stream>>>(big1, ss, big1);

    // Layer 2: 128 -> 256
    k_gemm<256><<<GB, 256, 0, stream>>>(big1, W2, big0, 128);
    k_agg<256><<<AB, 256, 0, stream>>>(big0, col, basep, deg, dinv, b2, big1);
    hipMemsetAsync(sums, 0, 512 * 4, stream);
    k_bnstats<256><<<512, 256, 0, stream>>>(big1, sums);
    k_bnfin<256><<<1, 256, 0, stream>>>(sums, g2, be2, ss);
    k_bnapply<256><<<(N_NODES * 256 / 4 + 255) / 256, 256, 0, stream>>>(big1, ss, big1);

    // Layer 3: 256 -> 128
    k_gemm<128><<<GB, 256, 0, stream>>>(big1, W3, big0, 256);
    k_agg<128><<<AB, 256, 0, stream>>>(big0, col, basep, deg, dinv, b3, big1);
    hipMemsetAsync(sums, 0, 512 * 4, stream);
    k_bnstats<128><<<512, 128, 0, stream>>>(big1, sums);
    k_bnfin<128><<<1, 128, 0, stream>>>(sums, g3, be3, ss);
    k_bnapply<128><<<(N_NODES * 128 / 4 + 255) / 256, 256, 0, stream>>>(big1, ss, big1);

    // Layer 4: 128 -> 64 (out4 and bn4 go to d_out)
    k_gemm<64><<<GB, 256, 0, stream>>>(big1, W4, big0, 128);
    k_agg<64><<<AB, 256, 0, stream>>>(big0, col, basep, deg, dinv, b4, out4);
    hipMemsetAsync(sums, 0, 512 * 4, stream);
    k_bnstats<64><<<512, 64, 0, stream>>>(out4, sums);
    k_bnfin<64><<<1, 64, 0, stream>>>(sums, g4, be4, ss);
    k_bnapply<64><<<(N_NODES * 64 / 4 + 255) / 256, 256, 0, stream>>>(out4, ss, bn4);

    // Classifier
    k_logits<<<(N_NODES + 255) / 256, 256, 0, stream>>>(bn4, Wc, bc, outLogits);
}

// Round 2
// 986.238 us; speedup vs baseline: 1.4350x; 1.4350x over previous
//
#include <hip/hip_runtime.h>
#include <hip/hip_bf16.h>

#define N_NODES 100000
#define N_EDGES 1600000

typedef short sh8 __attribute__((ext_vector_type(8)));
typedef float f32x4 __attribute__((ext_vector_type(4)));

__device__ __forceinline__ float bf2f(unsigned short s) {
    return __uint_as_float(((unsigned int)s) << 16);
}
__device__ __forceinline__ unsigned short f2bf(float f) {
    unsigned int u = __float_as_uint(f);
    unsigned int r = (u + 0x7FFFu + ((u >> 16) & 1u)) >> 16;
    return (unsigned short)r;
}

// ---------------- graph preprocessing ----------------

__global__ void k_count(const int* __restrict__ ei, int* __restrict__ deg) {
    int e = blockIdx.x * blockDim.x + threadIdx.x;
    if (e < N_EDGES) atomicAdd(&deg[ei[N_EDGES + e]], 1);
}

__global__ void k_dinv(const int* __restrict__ deg, float* __restrict__ dinv) {
    int i = blockIdx.x * blockDim.x + threadIdx.x;
    if (i < N_NODES) dinv[i] = rsqrtf((float)(deg[i] + 1)); // +1 self loop
}

__global__ void k_scan1(const int* __restrict__ deg, int* __restrict__ bsum) {
    __shared__ int sm[256];
    int t = threadIdx.x;
    int idx0 = blockIdx.x * 1024 + t * 4;
    int s = 0;
#pragma unroll
    for (int j = 0; j < 4; ++j) { int idx = idx0 + j; if (idx < N_NODES) s += deg[idx]; }
    sm[t] = s; __syncthreads();
    for (int d = 128; d > 0; d >>= 1) { if (t < d) sm[t] += sm[t + d]; __syncthreads(); }
    if (t == 0) bsum[blockIdx.x] = sm[0];
}

__global__ void k_scan2(int* __restrict__ bsum, int B) {
    __shared__ int sm[128];
    int t = threadIdx.x;
    int v = (t < B) ? bsum[t] : 0;
    sm[t] = v; __syncthreads();
    for (int d = 1; d < 128; d <<= 1) {
        int add = (t >= d) ? sm[t - d] : 0;
        __syncthreads(); sm[t] += add; __syncthreads();
    }
    if (t < B) bsum[t] = sm[t] - v; // exclusive
}

__global__ void k_scan3(const int* __restrict__ deg, const int* __restrict__ bsum,
                        int* __restrict__ basep, int* __restrict__ cursor) {
    __shared__ int sm[256];
    int t = threadIdx.x, b = blockIdx.x;
    int idx0 = b * 1024 + t * 4;
    int v[4]; int s = 0;
#pragma unroll
    for (int j = 0; j < 4; ++j) { int idx = idx0 + j; v[j] = (idx < N_NODES) ? deg[idx] : 0; s += v[j]; }
    sm[t] = s; __syncthreads();
    for (int d = 1; d < 256; d <<= 1) {
        int add = (t >= d) ? sm[t - d] : 0;
        __syncthreads(); sm[t] += add; __syncthreads();
    }
    int run = sm[t] - s + bsum[b];
#pragma unroll
    for (int j = 0; j < 4; ++j) {
        int idx = idx0 + j;
        if (idx < N_NODES) { basep[idx] = run; cursor[idx] = run; run += v[j]; }
    }
}

__global__ void k_scatter(const int* __restrict__ ei, int* __restrict__ cursor, int* __restrict__ col) {
    int e = blockIdx.x * blockDim.x + threadIdx.x;
    if (e < N_EDGES) {
        int s = ei[e], d = ei[N_EDGES + e];
        int pos = atomicAdd(&cursor[d], 1);
        col[pos] = s;
    }
}

// ---------------- W transpose + bf16 convert: Wt[n][k] = bf16(W[k][n]) ----------------

__global__ void k_wconv(const float* __restrict__ W, unsigned short* __restrict__ Wt, int K, int N) {
    int idx = blockIdx.x * 256 + threadIdx.x;
    if (idx >= K * N) return;
    int n = idx / K, k = idx - n * K;
    Wt[idx] = f2bf(W[(size_t)k * N + n]);
}

// ---------------- bf16 MFMA GEMM: Mout[m][col0+ n] = bf16( affine(A)[m][:] @ Wt[n][:] ) ----------------
// A: [M][K] (f32 or bf16), Wt: [NTOT][K] bf16 (pre-transposed), AFFINE: A'[m][k] = A[m][k]*ss[k]+ss[256+k]

template <int BN, int NWM, int NWN, bool F32IN, bool AFFINE>
__global__ __launch_bounds__(256) void k_gemm_bf(const void* __restrict__ Ain,
                                                 const unsigned short* __restrict__ Wt,
                                                 const float* __restrict__ ss,
                                                 unsigned short* __restrict__ Mout,
                                                 int K, int NTOT) {
    constexpr int BK = 64;
    constexpr int LDA = BK + 8; // pad: +16B per row, keeps 16B alignment, kills bank conflicts
    constexpr int MF = 128 / (16 * NWM);
    constexpr int NF = BN / (16 * NWN);
    __shared__ unsigned short As[128 * LDA];
    __shared__ unsigned short Bs[BN * LDA];
    const int tid = threadIdx.x;
    const int lane = tid & 63;
    const int w = tid >> 6;
    const int wm = w / NWN, wn = w % NWN;
    const int row0 = blockIdx.x * 128;
    const int col0 = blockIdx.y * BN;

    f32x4 acc[MF][NF];
#pragma unroll
    for (int i = 0; i < MF; ++i)
#pragma unroll
        for (int j = 0; j < NF; ++j)
#pragma unroll
            for (int r = 0; r < 4; ++r) acc[i][j][r] = 0.f;

    const int sr = tid >> 3;        // 0..31
    const int scc = (tid & 7) * 8;  // 0..56

    for (int k0 = 0; k0 < K; k0 += BK) {
        // ---- stage A tile (128 x 64 bf16), with optional f32-load / affine ----
#pragma unroll
        for (int p = 0; p < 4; ++p) {
            int r = p * 32 + sr;
            int gr = row0 + r;
            alignas(16) unsigned short tmp[8];
            if constexpr (F32IN) {
                const float* Af = (const float*)Ain;
                float4 v0 = make_float4(0.f, 0.f, 0.f, 0.f), v1 = v0;
                if (gr < N_NODES) {
                    const float* p0 = Af + (size_t)gr * K + k0 + scc;
                    v0 = *(const float4*)p0;
                    v1 = *(const float4*)(p0 + 4);
                }
                tmp[0] = f2bf(v0.x); tmp[1] = f2bf(v0.y); tmp[2] = f2bf(v0.z); tmp[3] = f2bf(v0.w);
                tmp[4] = f2bf(v1.x); tmp[5] = f2bf(v1.y); tmp[6] = f2bf(v1.z); tmp[7] = f2bf(v1.w);
            } else {
                const unsigned short* Ab = (const unsigned short*)Ain;
                uint4 raw = make_uint4(0, 0, 0, 0);
                if (gr < N_NODES) raw = *(const uint4*)(Ab + (size_t)gr * K + k0 + scc);
                if constexpr (AFFINE) {
                    const unsigned short* pr = (const unsigned short*)&raw;
                    float4 s0 = *(const float4*)&ss[k0 + scc];
                    float4 s1 = *(const float4*)&ss[k0 + scc + 4];
                    float4 h0 = *(const float4*)&ss[256 + k0 + scc];
                    float4 h1 = *(const float4*)&ss[256 + k0 + scc + 4];
                    tmp[0] = f2bf(bf2f(pr[0]) * s0.x + h0.x);
                    tmp[1] = f2bf(bf2f(pr[1]) * s0.y + h0.y);
                    tmp[2] = f2bf(bf2f(pr[2]) * s0.z + h0.z);
                    tmp[3] = f2bf(bf2f(pr[3]) * s0.w + h0.w);
                    tmp[4] = f2bf(bf2f(pr[4]) * s1.x + h1.x);
                    tmp[5] = f2bf(bf2f(pr[5]) * s1.y + h1.y);
                    tmp[6] = f2bf(bf2f(pr[6]) * s1.z + h1.z);
                    tmp[7] = f2bf(bf2f(pr[7]) * s1.w + h1.w);
                } else {
                    *(uint4*)tmp = raw;
                }
            }
            *(uint4*)&As[r * LDA + scc] = *(const uint4*)tmp;
        }
        // ---- stage B tile (BN x 64 bf16) from Wt rows ----
        constexpr int BP = (BN * BK) / 2048;
#pragma unroll
        for (int p = 0; p < BP; ++p) {
            int r = p * 32 + sr;
            uint4 raw = *(const uint4*)(Wt + (size_t)(col0 + r) * K + k0 + scc);
            *(uint4*)&Bs[r * LDA + scc] = raw;
        }
        __syncthreads();
        // ---- MFMA: two K=32 sub-steps ----
#pragma unroll
        for (int ks = 0; ks < 2; ++ks) {
            sh8 af[MF], bfr[NF];
#pragma unroll
            for (int i = 0; i < MF; ++i)
                af[i] = *(const sh8*)&As[(wm * MF * 16 + i * 16 + (lane & 15)) * LDA + ks * 32 + (lane >> 4) * 8];
#pragma unroll
            for (int j = 0; j < NF; ++j)
                bfr[j] = *(const sh8*)&Bs[(wn * NF * 16 + j * 16 + (lane & 15)) * LDA + ks * 32 + (lane >> 4) * 8];
#pragma unroll
            for (int i = 0; i < MF; ++i)
#pragma unroll
                for (int j = 0; j < NF; ++j)
                    acc[i][j] = __builtin_amdgcn_mfma_f32_16x16x32_bf16(af[i], bfr[j], acc[i][j], 0, 0, 0);
        }
        __syncthreads();
    }
    // ---- epilogue: C[row][col], row=(lane>>4)*4+r, col=lane&15 ----
#pragma unroll
    for (int i = 0; i < MF; ++i) {
#pragma unroll
        for (int r = 0; r < 4; ++r) {
            int grow = row0 + wm * MF * 16 + i * 16 + (lane >> 4) * 4 + r;
            if (grow >= N_NODES) continue;
#pragma unroll
            for (int j = 0; j < NF; ++j) {
                int gcol = col0 + wn * NF * 16 + j * 16 + (lane & 15);
                Mout[(size_t)grow * NTOT + gcol] = f2bf(acc[i][j][r]);
            }
        }
    }
}

// ---------------- aggregation over bf16 messages ----------------
// out = relu(dinv_dst*(sum_edges dinv_src*m[src] + dinv_dst*m[self]) + b), wave per node

template <int D, bool OUTF32>
__global__ __launch_bounds__(256) void k_aggb(const unsigned short* __restrict__ m,
                                              const int* __restrict__ col,
                                              const int* __restrict__ basep,
                                              const int* __restrict__ deg,
                                              const float* __restrict__ dinv,
                                              const float* __restrict__ bias,
                                              void* __restrict__ out) {
    constexpr int VPL = D / 64;
    int w = (blockIdx.x * 256 + threadIdx.x) >> 6;
    if (w >= N_NODES) return;
    int lane = threadIdx.x & 63;
    int fo = lane * VPL;
    float acc[VPL];
#pragma unroll
    for (int k = 0; k < VPL; ++k) acc[k] = 0.f;

    auto addrow = [&](int s, float c) {
        const unsigned short* r = m + (size_t)s * D + fo;
        if constexpr (VPL == 4) {
            uint2 u = *(const uint2*)r;
            acc[0] += c * __uint_as_float(u.x << 16);
            acc[1] += c * __uint_as_float(u.x & 0xffff0000u);
            acc[2] += c * __uint_as_float(u.y << 16);
            acc[3] += c * __uint_as_float(u.y & 0xffff0000u);
        } else if constexpr (VPL == 2) {
            unsigned int u = *(const unsigned int*)r;
            acc[0] += c * __uint_as_float(u << 16);
            acc[1] += c * __uint_as_float(u & 0xffff0000u);
        } else {
            acc[0] += c * bf2f(r[0]);
        }
    };

    int start = basep[w], cnt = deg[w];
    int j = 0;
    for (; j + 2 <= cnt; j += 2) {
        int s0 = col[start + j], s1 = col[start + j + 1];
        float c0 = dinv[s0], c1 = dinv[s1];
        addrow(s0, c0);
        addrow(s1, c1);
    }
    if (j < cnt) { int s0 = col[start + j]; addrow(s0, dinv[s0]); }
    float di = dinv[w];
    addrow(w, di);

    float o[VPL];
#pragma unroll
    for (int k = 0; k < VPL; ++k) o[k] = fmaxf(acc[k] * di + bias[fo + k], 0.f);

    if constexpr (OUTF32) {
        float* of = (float*)out;
#pragma unroll
        for (int k = 0; k < VPL; ++k) of[(size_t)w * D + fo + k] = o[k];
    } else {
        unsigned short* ob = (unsigned short*)out + (size_t)w * D + fo;
        if constexpr (VPL == 4) {
            uint2 u;
            u.x = (unsigned)f2bf(o[0]) | ((unsigned)f2bf(o[1]) << 16);
            u.y = (unsigned)f2bf(o[2]) | ((unsigned)f2bf(o[3]) << 16);
            *(uint2*)ob = u;
        } else if constexpr (VPL == 2) {
            unsigned int u = (unsigned)f2bf(o[0]) | ((unsigned)f2bf(o[1]) << 16);
            *(unsigned int*)ob = u;
        } else {
            ob[0] = f2bf(o[0]);
        }
    }
}

// ---------------- BatchNorm stats / finalize ----------------

template <int D, bool INF32>
__global__ void k_bnstats2(const void* __restrict__ h, float* __restrict__ sums) {
    int f = threadIdx.x; // blockDim == D
    float s = 0.f, s2 = 0.f;
    for (int r = blockIdx.x; r < N_NODES; r += gridDim.x) {
        float v;
        if constexpr (INF32) v = ((const float*)h)[(size_t)r * D + f];
        else v = bf2f(((const unsigned short*)h)[(size_t)r * D + f]);
        s += v; s2 += v * v;
    }
    atomicAdd(&sums[f], s);
    atomicAdd(&sums[256 + f], s2);
}

template <int D>
__global__ void k_bnfin(const float* __restrict__ sums, const float* __restrict__ gamma,
                        const float* __restrict__ beta, float* __restrict__ ss) {
    int f = threadIdx.x; // blockDim == D
    float mean = sums[f] * (1.f / N_NODES);
    float var = sums[256 + f] * (1.f / N_NODES) - mean * mean;
    float inv = rsqrtf(var + 1e-5f);
    float sc = gamma[f] * inv;
    ss[f] = sc;
    ss[256 + f] = beta[f] - mean * sc;
}

// ---------------- layer-4 BN apply + classifier (wave per node) ----------------

__global__ __launch_bounds__(256) void k_bnlog(const float* __restrict__ out4, const float* __restrict__ ss,
                                               const float* __restrict__ Wc, const float* __restrict__ bc,
                                               float* __restrict__ bn4, float* __restrict__ logits) {
    int gw = (blockIdx.x * 256 + threadIdx.x) >> 6;
    if (gw >= N_NODES) return;
    int f = threadIdx.x & 63;
    float v = out4[(size_t)gw * 64 + f];
    float bn = v * ss[f] + ss[256 + f];
    bn4[(size_t)gw * 64 + f] = bn;
    float a0 = bn * Wc[2 * f];
    float a1 = bn * Wc[2 * f + 1];
#pragma unroll
    for (int off = 32; off; off >>= 1) {
        a0 += __shfl_down(a0, off, 64);
        a1 += __shfl_down(a1, off, 64);
    }
    if (f == 0) {
        float l0 = a0 + bc[0], l1 = a1 + bc[1];
        logits[2 * gw] = l0;
        logits[2 * gw + 1] = l1;
    }
}

// ---------------- launch ----------------

extern "C" void kernel_launch(void* const* d_in, const int* in_sizes, int n_in,
                              void* d_out, int out_size, void* d_ws, size_t ws_size,
                              hipStream_t stream) {
    const float* x  = (const float*)d_in[0];
    const int* ei   = (const int*)d_in[1];
    const float* W1 = (const float*)d_in[2];  const float* b1  = (const float*)d_in[3];
    const float* W2 = (const float*)d_in[4];  const float* b2  = (const float*)d_in[5];
    const float* W3 = (const float*)d_in[6];  const float* b3  = (const float*)d_in[7];
    const float* W4 = (const float*)d_in[8];  const float* b4  = (const float*)d_in[9];
    const float* Wc = (const float*)d_in[10]; const float* bc  = (const float*)d_in[11];
    const float* g1 = (const float*)d_in[12]; const float* be1 = (const float*)d_in[13];
    const float* g2 = (const float*)d_in[14]; const float* be2 = (const float*)d_in[15];
    const float* g3 = (const float*)d_in[16]; const float* be3 = (const float*)d_in[17];
    const float* g4 = (const float*)d_in[18]; const float* be4 = (const float*)d_in[19];

    char* wsb = (char*)d_ws;
    size_t off = 0;
    auto alloc = [&](size_t bytes) -> void* {
        void* p = wsb + off;
        off = (off + bytes + 511) & ~(size_t)511;
        return p;
    };
    int* deg    = (int*)alloc((size_t)N_NODES * 4);
    int* basep  = (int*)alloc((size_t)N_NODES * 4);
    int* cursor = (int*)alloc((size_t)N_NODES * 4);
    float* dinv = (float*)alloc((size_t)N_NODES * 4);
    int* col    = (int*)alloc((size_t)N_EDGES * 4);
    int* bsum   = (int*)alloc(128 * 4);
    float* sums = (float*)alloc(512 * 4);
    float* ss   = (float*)alloc(512 * 4);
    unsigned short* Wt1 = (unsigned short*)alloc((size_t)256 * 128 * 2);
    unsigned short* Wt2 = (unsigned short*)alloc((size_t)128 * 256 * 2);
    unsigned short* Wt3 = (unsigned short*)alloc((size_t)256 * 128 * 2);
    unsigned short* Wt4 = (unsigned short*)alloc((size_t)128 * 64 * 2);
    unsigned short* mb = (unsigned short*)alloc((size_t)N_NODES * 256 * 2);
    unsigned short* hb = (unsigned short*)alloc((size_t)N_NODES * 256 * 2);

    float* outLogits = (float*)d_out;
    float* out4 = outLogits + (size_t)N_NODES * 2;
    float* bn4  = out4 + (size_t)N_NODES * 64;

    hipMemsetAsync(deg, 0, (size_t)N_NODES * 4, stream);
    const int B1 = (N_NODES + 1023) / 1024; // 98
    k_count<<<(N_EDGES + 255) / 256, 256, 0, stream>>>(ei, deg);
    k_dinv<<<(N_NODES + 255) / 256, 256, 0, stream>>>(deg, dinv);
    k_scan1<<<B1, 256, 0, stream>>>(deg, bsum);
    k_scan2<<<1, 128, 0, stream>>>(bsum, B1);
    k_scan3<<<B1, 256, 0, stream>>>(deg, bsum, basep, cursor);
    k_scatter<<<(N_EDGES + 255) / 256, 256, 0, stream>>>(ei, cursor, col);

    k_wconv<<<(256 * 128 + 255) / 256, 256, 0, stream>>>(W1, Wt1, 256, 128);
    k_wconv<<<(128 * 256 + 255) / 256, 256, 0, stream>>>(W2, Wt2, 128, 256);
    k_wconv<<<(256 * 128 + 255) / 256, 256, 0, stream>>>(W3, Wt3, 256, 128);
    k_wconv<<<(128 * 64 + 255) / 256, 256, 0, stream>>>(W4, Wt4, 128, 64);

    const int GBM = (N_NODES + 127) / 128; // 782
    const int AB = (N_NODES + 3) / 4;      // wave per node, 4 nodes/block

    // Layer 1: x(f32,256) -> m(128) ; agg -> h ; BN stats
    k_gemm_bf<128, 2, 2, true, false><<<dim3(GBM, 1), 256, 0, stream>>>(x, Wt1, nullptr, mb, 256, 128);
    k_aggb<128, false><<<AB, 256, 0, stream>>>(mb, col, basep, deg, dinv, b1, hb);
    hipMemsetAsync(sums, 0, 512 * 4, stream);
    k_bnstats2<128, false><<<512, 128, 0, stream>>>(hb, sums);
    k_bnfin<128><<<1, 128, 0, stream>>>(sums, g1, be1, ss);

    // Layer 2: h(bf16,128, affine ss) -> m(256) ; agg -> h ; BN stats
    k_gemm_bf<128, 2, 2, false, true><<<dim3(GBM, 2), 256, 0, stream>>>(hb, Wt2, ss, mb, 128, 256);
    k_aggb<256, false><<<AB, 256, 0, stream>>>(mb, col, basep, deg, dinv, b2, hb);
    hipMemsetAsync(sums, 0, 512 * 4, stream);
    k_bnstats2<256, false><<<512, 256, 0, stream>>>(hb, sums);
    k_bnfin<256><<<1, 256, 0, stream>>>(sums, g2, be2, ss);

    // Layer 3: h(bf16,256, affine) -> m(128) ; agg -> h ; BN stats
    k_gemm_bf<128, 2, 2, false, true><<<dim3(GBM, 1), 256, 0, stream>>>(hb, Wt3, ss, mb, 256, 128);
    k_aggb<128, false><<<AB, 256, 0, stream>>>(mb, col, basep, deg, dinv, b3, hb);
    hipMemsetAsync(sums, 0, 512 * 4, stream);
    k_bnstats2<128, false><<<512, 128, 0, stream>>>(hb, sums);
    k_bnfin<128><<<1, 128, 0, stream>>>(sums, g3, be3, ss);

    // Layer 4: h(bf16,128, affine) -> m(64) ; agg -> out4 (f32) ; BN ; classifier
    k_gemm_bf<64, 4, 1, false, true><<<dim3(GBM, 1), 256, 0, stream>>>(hb, Wt4, ss, mb, 128, 64);
    k_aggb<64, true><<<AB, 256, 0, stream>>>(mb, col, basep, deg, dinv, b4, out4);
    hipMemsetAsync(sums, 0, 512 * 4, stream);
    k_bnstats2<64, true><<<512, 64, 0, stream>>>(out4, sums);
    k_bnfin<64><<<1, 64, 0, stream>>>(sums, g4, be4, ss);
    k_bnlog<<<(N_NODES * 64 + 255) / 256, 256, 0, stream>>>(out4, ss, Wc, bc, bn4, outLogits);
}

// Round 3
// 868.503 us; speedup vs baseline: 1.6296x; 1.1356x over previous
//
#include <hip/hip_runtime.h>
#include <hip/hip_bf16.h>

#define N_NODES 100000
#define N_EDGES 1600000
#define NB ((N_NODES + 255) / 256)   // 391 dst-buckets of 256

typedef short sh8 __attribute__((ext_vector_type(8)));
typedef float f32x4 __attribute__((ext_vector_type(4)));

__device__ __forceinline__ float bf2f(unsigned short s) {
    return __uint_as_float(((unsigned int)s) << 16);
}
__device__ __forceinline__ unsigned short f2bf(float f) {
    unsigned int u = __float_as_uint(f);
    unsigned int r = (u + 0x7FFFu + ((u >> 16) & 1u)) >> 16;
    return (unsigned short)r;
}
__device__ __forceinline__ float blo(unsigned int u) { return __uint_as_float(u << 16); }
__device__ __forceinline__ float bhi(unsigned int u) { return __uint_as_float(u & 0xffff0000u); }

// ---------------- graph preprocessing: bucket counting sort -> CSR ----------------
// counters padded to 64B (stride 16 ints) to avoid same-line atomic serialization

__global__ void k_bcount(const int* __restrict__ ei, int* __restrict__ bcnt) {
    int e = blockIdx.x * 256 + threadIdx.x;
    if (e < N_EDGES) atomicAdd(&bcnt[(ei[N_EDGES + e] >> 8) * 16], 1);
}

__global__ void k_bscan(const int* __restrict__ bcnt, int* __restrict__ bbase, int* __restrict__ bcur) {
    __shared__ int sm[512];
    int t = threadIdx.x;
    int v = (t < NB) ? bcnt[t * 16] : 0;
    sm[t] = v; __syncthreads();
    for (int d = 1; d < 512; d <<= 1) {
        int add = (t >= d) ? sm[t - d] : 0;
        __syncthreads(); sm[t] += add; __syncthreads();
    }
    int excl = sm[t] - v;
    if (t <= NB) bbase[t] = excl;
    if (t < NB) bcur[t * 16] = excl;
}

__global__ void k_bscat(const int* __restrict__ ei, int* __restrict__ bcur, uint2* __restrict__ pairs) {
    int e = blockIdx.x * 256 + threadIdx.x;
    if (e < N_EDGES) {
        int s = ei[e], d = ei[N_EDGES + e];
        int pos = atomicAdd(&bcur[(d >> 8) * 16], 1);
        pairs[pos] = make_uint2((unsigned)s, (unsigned)d);
    }
}

__global__ __launch_bounds__(256) void k_bsort(const uint2* __restrict__ pairs, const int* __restrict__ bbase,
                                               int* __restrict__ col, int* __restrict__ basep,
                                               int* __restrict__ deg, float* __restrict__ dinv) {
    __shared__ int cnt[256];
    __shared__ int sm[256];
    __shared__ int cur[256];
    int b = blockIdx.x, t = threadIdx.x;
    int base = bbase[b], end = bbase[b + 1];
    int d0 = b << 8;
    cnt[t] = 0; __syncthreads();
    for (int e = base + t; e < end; e += 256) atomicAdd(&cnt[pairs[e].y & 255], 1);
    __syncthreads();
    int v = cnt[t];
    sm[t] = v; __syncthreads();
    for (int d = 1; d < 256; d <<= 1) {
        int add = (t >= d) ? sm[t - d] : 0;
        __syncthreads(); sm[t] += add; __syncthreads();
    }
    int excl = sm[t] - v;
    cur[t] = excl;
    int gd = d0 + t;
    if (gd < N_NODES) {
        basep[gd] = base + excl;
        deg[gd] = v;
        dinv[gd] = rsqrtf((float)(v + 1));
    }
    __syncthreads();
    for (int e = base + t; e < end; e += 256) {
        uint2 p = pairs[e];
        int pos = atomicAdd(&cur[p.y & 255], 1);
        col[base + pos] = (int)p.x;
    }
}

// ---------------- W transpose + bf16 convert: Wt[n][k] = bf16(W[k][n]) ----------------

__global__ void k_wconv(const float* __restrict__ W, unsigned short* __restrict__ Wt, int K, int N) {
    int idx = blockIdx.x * 256 + threadIdx.x;
    if (idx >= K * N) return;
    int n = idx / K, k = idx - n * K;
    Wt[idx] = f2bf(W[(size_t)k * N + n]);
}

// ---------------- bf16 MFMA GEMM ----------------
// AMODE: 0 = f32 input plain; 1 = bf16 input, A'=ss[k]*A+ss[256+k]; 2 = bf16, A'=ss[k]*A+ss[256+k]*svec[row]
// BIASRELU: epilogue out = relu(acc + bias[col])

template <int BN, int NWM, int NWN, int AMODE, bool BIASRELU>
__global__ __launch_bounds__(256) void k_gemm_bf(const void* __restrict__ Ain,
                                                 const unsigned short* __restrict__ Wt,
                                                 const float* __restrict__ ss,
                                                 const float* __restrict__ svec,
                                                 const float* __restrict__ bias,
                                                 unsigned short* __restrict__ Mout,
                                                 int K, int NTOT) {
    constexpr int BK = 64;
    constexpr int LDA = BK + 8;
    constexpr int MF = 128 / (16 * NWM);
    constexpr int NF = BN / (16 * NWN);
    __shared__ unsigned short As[128 * LDA];
    __shared__ unsigned short Bs[BN * LDA];
    const int tid = threadIdx.x;
    const int lane = tid & 63;
    const int w = tid >> 6;
    const int wm = w / NWN, wn = w % NWN;
    const int row0 = blockIdx.x * 128;
    const int col0 = blockIdx.y * BN;

    f32x4 acc[MF][NF];
#pragma unroll
    for (int i = 0; i < MF; ++i)
#pragma unroll
        for (int j = 0; j < NF; ++j)
#pragma unroll
            for (int r = 0; r < 4; ++r) acc[i][j][r] = 0.f;

    const int sr = tid >> 3;        // 0..31
    const int scc = (tid & 7) * 8;  // 0..56

    for (int k0 = 0; k0 < K; k0 += BK) {
#pragma unroll
        for (int p = 0; p < 4; ++p) {
            int r = p * 32 + sr;
            int gr = row0 + r;
            alignas(16) unsigned short tmp[8];
            if constexpr (AMODE == 0) {
                const float* Af = (const float*)Ain;
                float4 v0 = make_float4(0.f, 0.f, 0.f, 0.f), v1 = v0;
                if (gr < N_NODES) {
                    const float* p0 = Af + (size_t)gr * K + k0 + scc;
                    v0 = *(const float4*)p0;
                    v1 = *(const float4*)(p0 + 4);
                }
                tmp[0] = f2bf(v0.x); tmp[1] = f2bf(v0.y); tmp[2] = f2bf(v0.z); tmp[3] = f2bf(v0.w);
                tmp[4] = f2bf(v1.x); tmp[5] = f2bf(v1.y); tmp[6] = f2bf(v1.z); tmp[7] = f2bf(v1.w);
            } else {
                const unsigned short* Ab = (const unsigned short*)Ain;
                uint4 raw = make_uint4(0, 0, 0, 0);
                if (gr < N_NODES) raw = *(const uint4*)(Ab + (size_t)gr * K + k0 + scc);
                const unsigned short* pr = (const unsigned short*)&raw;
                float sv = 1.f;
                if constexpr (AMODE == 2) sv = (gr < N_NODES) ? svec[gr] : 0.f;
#pragma unroll
                for (int q = 0; q < 8; ++q) {
                    float sc = ss[k0 + scc + q];
                    float sh = ss[256 + k0 + scc + q];
                    float val;
                    if constexpr (AMODE == 2) val = bf2f(pr[q]) * sc + sh * sv;
                    else val = bf2f(pr[q]) * sc + sh;
                    tmp[q] = f2bf(val);
                }
            }
            *(uint4*)&As[r * LDA + scc] = *(const uint4*)tmp;
        }
        constexpr int BP = (BN * BK) / 2048;
#pragma unroll
        for (int p = 0; p < BP; ++p) {
            int r = p * 32 + sr;
            uint4 raw = *(const uint4*)(Wt + (size_t)(col0 + r) * K + k0 + scc);
            *(uint4*)&Bs[r * LDA + scc] = raw;
        }
        __syncthreads();
#pragma unroll
        for (int ks = 0; ks < 2; ++ks) {
            sh8 af[MF], bfr[NF];
#pragma unroll
            for (int i = 0; i < MF; ++i)
                af[i] = *(const sh8*)&As[(wm * MF * 16 + i * 16 + (lane & 15)) * LDA + ks * 32 + (lane >> 4) * 8];
#pragma unroll
            for (int j = 0; j < NF; ++j)
                bfr[j] = *(const sh8*)&Bs[(wn * NF * 16 + j * 16 + (lane & 15)) * LDA + ks * 32 + (lane >> 4) * 8];
#pragma unroll
            for (int i = 0; i < MF; ++i)
#pragma unroll
                for (int j = 0; j < NF; ++j)
                    acc[i][j] = __builtin_amdgcn_mfma_f32_16x16x32_bf16(af[i], bfr[j], acc[i][j], 0, 0, 0);
        }
        __syncthreads();
    }
#pragma unroll
    for (int i = 0; i < MF; ++i) {
#pragma unroll
        for (int r = 0; r < 4; ++r) {
            int grow = row0 + wm * MF * 16 + i * 16 + (lane >> 4) * 4 + r;
            if (grow >= N_NODES) continue;
#pragma unroll
            for (int j = 0; j < NF; ++j) {
                int gcol = col0 + wn * NF * 16 + j * 16 + (lane & 15);
                float v = acc[i][j][r];
                if constexpr (BIASRELU) v = fmaxf(v + bias[gcol], 0.f);
                Mout[(size_t)grow * NTOT + gcol] = f2bf(v);
            }
        }
    }
}

// ---------------- aggregation (wave per node, unroll-4 gather) ----------------
// POST (PRE=false): out = relu(dinv_dst*(sum dinv_src*m[src] + dinv_dst*m[self]) + bias)
// PRE  (PRE=true):  out = dinv_dst*(sum dinv_src*m[src] + dinv_dst*m[self]);  svec = dinv_dst*(sum dinv_src + dinv_dst)

template <int D, bool PRE, bool OUTF32>
__global__ __launch_bounds__(256) void k_agg2(const unsigned short* __restrict__ m,
                                              const int* __restrict__ col,
                                              const int* __restrict__ basep,
                                              const int* __restrict__ deg,
                                              const float* __restrict__ dinv,
                                              const float* __restrict__ bias,
                                              void* __restrict__ out,
                                              float* __restrict__ svec) {
    constexpr int VPL = D / 64;
    int w = (blockIdx.x * 256 + threadIdx.x) >> 6;
    if (w >= N_NODES) return;
    int lane = threadIdx.x & 63;
    int fo = lane * VPL;
    const unsigned short* mfo = m + fo;
    float acc[VPL];
    float accs = 0.f;
#pragma unroll
    for (int k = 0; k < VPL; ++k) acc[k] = 0.f;

    int start = basep[w], cnt = deg[w];
    int j = 0;
    for (; j + 4 <= cnt; j += 4) {
        int s0 = col[start + j], s1 = col[start + j + 1];
        int s2 = col[start + j + 2], s3 = col[start + j + 3];
        float c0 = dinv[s0], c1 = dinv[s1], c2 = dinv[s2], c3 = dinv[s3];
        if constexpr (VPL == 2) {
            unsigned u0 = *(const unsigned*)(mfo + (size_t)s0 * D);
            unsigned u1 = *(const unsigned*)(mfo + (size_t)s1 * D);
            unsigned u2 = *(const unsigned*)(mfo + (size_t)s2 * D);
            unsigned u3 = *(const unsigned*)(mfo + (size_t)s3 * D);
            acc[0] += c0 * blo(u0) + c1 * blo(u1) + c2 * blo(u2) + c3 * blo(u3);
            acc[1] += c0 * bhi(u0) + c1 * bhi(u1) + c2 * bhi(u2) + c3 * bhi(u3);
        } else {
            float v0 = bf2f(mfo[(size_t)s0 * D]);
            float v1 = bf2f(mfo[(size_t)s1 * D]);
            float v2 = bf2f(mfo[(size_t)s2 * D]);
            float v3 = bf2f(mfo[(size_t)s3 * D]);
            acc[0] += c0 * v0 + c1 * v1 + c2 * v2 + c3 * v3;
        }
        if constexpr (PRE) accs += c0 + c1 + c2 + c3;
    }
    for (; j < cnt; ++j) {
        int s0 = col[start + j];
        float c0 = dinv[s0];
        if constexpr (VPL == 2) {
            unsigned u0 = *(const unsigned*)(mfo + (size_t)s0 * D);
            acc[0] += c0 * blo(u0); acc[1] += c0 * bhi(u0);
        } else {
            acc[0] += c0 * bf2f(mfo[(size_t)s0 * D]);
        }
        if constexpr (PRE) accs += c0;
    }
    float di = dinv[w];
    if constexpr (VPL == 2) {
        unsigned u0 = *(const unsigned*)(mfo + (size_t)w * D);
        acc[0] += di * blo(u0); acc[1] += di * bhi(u0);
    } else {
        acc[0] += di * bf2f(mfo[(size_t)w * D]);
    }
    if constexpr (PRE) accs += di;

    float o[VPL];
    if constexpr (PRE) {
#pragma unroll
        for (int k = 0; k < VPL; ++k) o[k] = acc[k] * di;
        if (lane == 0) svec[w] = accs * di;
    } else {
#pragma unroll
        for (int k = 0; k < VPL; ++k) o[k] = fmaxf(acc[k] * di + bias[fo + k], 0.f);
    }

    if constexpr (OUTF32) {
        float* of = (float*)out;
#pragma unroll
        for (int k = 0; k < VPL; ++k) of[(size_t)w * D + fo + k] = o[k];
    } else {
        unsigned short* ob = (unsigned short*)out + (size_t)w * D + fo;
        if constexpr (VPL == 2) {
            unsigned int u = (unsigned)f2bf(o[0]) | ((unsigned)f2bf(o[1]) << 16);
            *(unsigned int*)ob = u;
        } else {
            ob[0] = f2bf(o[0]);
        }
    }
}

// ---------------- BatchNorm stats / finalize ----------------

template <int D, bool INF32>
__global__ void k_bnstats2(const void* __restrict__ h, float* __restrict__ sums) {
    int f = threadIdx.x; // blockDim == D
    float s = 0.f, s2 = 0.f;
    for (int r = blockIdx.x; r < N_NODES; r += gridDim.x) {
        float v;
        if constexpr (INF32) v = ((const float*)h)[(size_t)r * D + f];
        else v = bf2f(((const unsigned short*)h)[(size_t)r * D + f]);
        s += v; s2 += v * v;
    }
    atomicAdd(&sums[f], s);
    atomicAdd(&sums[256 + f], s2);
}

template <int D>
__global__ void k_bnfin(const float* __restrict__ sums, const float* __restrict__ gamma,
                        const float* __restrict__ beta, float* __restrict__ ss) {
    int f = threadIdx.x; // blockDim == D
    float mean = sums[f] * (1.f / N_NODES);
    float var = sums[256 + f] * (1.f / N_NODES) - mean * mean;
    float inv = rsqrtf(var + 1e-5f);
    float sc = gamma[f] * inv;
    ss[f] = sc;
    ss[256 + f] = beta[f] - mean * sc;
}

// ---------------- layer-4 BN apply + classifier (wave per node) ----------------

__global__ __launch_bounds__(256) void k_bnlog(const float* __restrict__ out4, const float* __restrict__ ss,
                                               const float* __restrict__ Wc, const float* __restrict__ bc,
                                               float* __restrict__ bn4, float* __restrict__ logits) {
    int gw = (blockIdx.x * 256 + threadIdx.x) >> 6;
    if (gw >= N_NODES) return;
    int f = threadIdx.x & 63;
    float v = out4[(size_t)gw * 64 + f];
    float bn = v * ss[f] + ss[256 + f];
    bn4[(size_t)gw * 64 + f] = bn;
    float a0 = bn * Wc[2 * f];
    float a1 = bn * Wc[2 * f + 1];
#pragma unroll
    for (int off = 32; off; off >>= 1) {
        a0 += __shfl_down(a0, off, 64);
        a1 += __shfl_down(a1, off, 64);
    }
    if (f == 0) {
        logits[2 * gw] = a0 + bc[0];
        logits[2 * gw + 1] = a1 + bc[1];
    }
}

// ---------------- launch ----------------

extern "C" void kernel_launch(void* const* d_in, const int* in_sizes, int n_in,
                              void* d_out, int out_size, void* d_ws, size_t ws_size,
                              hipStream_t stream) {
    const float* x  = (const float*)d_in[0];
    const int* ei   = (const int*)d_in[1];
    const float* W1 = (const float*)d_in[2];  const float* b1  = (const float*)d_in[3];
    const float* W2 = (const float*)d_in[4];  const float* b2  = (const float*)d_in[5];
    const float* W3 = (const float*)d_in[6];  const float* b3  = (const float*)d_in[7];
    const float* W4 = (const float*)d_in[8];  const float* b4  = (const float*)d_in[9];
    const float* Wc = (const float*)d_in[10]; const float* bc  = (const float*)d_in[11];
    const float* g1 = (const float*)d_in[12]; const float* be1 = (const float*)d_in[13];
    const float* g2 = (const float*)d_in[14]; const float* be2 = (const float*)d_in[15];
    const float* g3 = (const float*)d_in[16]; const float* be3 = (const float*)d_in[17];
    const float* g4 = (const float*)d_in[18]; const float* be4 = (const float*)d_in[19];

    char* wsb = (char*)d_ws;
    size_t off = 0;
    auto alloc = [&](size_t bytes) -> void* {
        void* p = wsb + off;
        off = (off + bytes + 511) & ~(size_t)511;
        return p;
    };
    int* deg    = (int*)alloc((size_t)N_NODES * 4);
    int* basep  = (int*)alloc((size_t)N_NODES * 4);
    float* dinv = (float*)alloc((size_t)N_NODES * 4);
    float* svec = (float*)alloc((size_t)N_NODES * 4);
    int* col    = (int*)alloc((size_t)N_EDGES * 4);
    uint2* pairs = (uint2*)alloc((size_t)N_EDGES * 8);
    int* bcnt   = (int*)alloc((size_t)NB * 16 * 4);
    int* bbase  = (int*)alloc((size_t)(NB + 1) * 4);
    int* bcur   = (int*)alloc((size_t)NB * 16 * 4);
    float* sums = (float*)alloc(512 * 4);
    float* ss   = (float*)alloc(512 * 4);
    unsigned short* Wt1 = (unsigned short*)alloc((size_t)256 * 128 * 2);
    unsigned short* Wt2 = (unsigned short*)alloc((size_t)128 * 256 * 2);
    unsigned short* Wt3 = (unsigned short*)alloc((size_t)256 * 128 * 2);
    unsigned short* Wt4 = (unsigned short*)alloc((size_t)128 * 64 * 2);
    unsigned short* mb = (unsigned short*)alloc((size_t)N_NODES * 128 * 2);
    unsigned short* hb = (unsigned short*)alloc((size_t)N_NODES * 256 * 2);

    float* outLogits = (float*)d_out;
    float* out4 = outLogits + (size_t)N_NODES * 2;
    float* bn4  = out4 + (size_t)N_NODES * 64;

    // ---- CSR build via bucket counting sort ----
    hipMemsetAsync(bcnt, 0, (size_t)NB * 16 * 4, stream);
    k_bcount<<<(N_EDGES + 255) / 256, 256, 0, stream>>>(ei, bcnt);
    k_bscan<<<1, 512, 0, stream>>>(bcnt, bbase, bcur);
    k_bscat<<<(N_EDGES + 255) / 256, 256, 0, stream>>>(ei, bcur, pairs);
    k_bsort<<<NB, 256, 0, stream>>>(pairs, bbase, col, basep, deg, dinv);

    k_wconv<<<(256 * 128 + 255) / 256, 256, 0, stream>>>(W1, Wt1, 256, 128);
    k_wconv<<<(128 * 256 + 255) / 256, 256, 0, stream>>>(W2, Wt2, 128, 256);
    k_wconv<<<(256 * 128 + 255) / 256, 256, 0, stream>>>(W3, Wt3, 256, 128);
    k_wconv<<<(128 * 64 + 255) / 256, 256, 0, stream>>>(W4, Wt4, 128, 64);

    const int GBM = (N_NODES + 127) / 128; // 782
    const int AB = (N_NODES + 3) / 4;      // wave per node, 4 nodes/block

    // Layer 1: x(f32,256) @ W1 -> m1(128); agg+b1+relu -> h1(hb); BN1 stats
    k_gemm_bf<128, 2, 2, 0, false><<<dim3(GBM, 1), 256, 0, stream>>>(x, Wt1, nullptr, nullptr, nullptr, mb, 256, 128);
    k_agg2<128, false, false><<<AB, 256, 0, stream>>>(mb, col, basep, deg, dinv, b1, hb, nullptr);
    hipMemsetAsync(sums, 0, 512 * 4, stream);
    k_bnstats2<128, false><<<512, 128, 0, stream>>>(hb, sums);
    k_bnfin<128><<<1, 128, 0, stream>>>(sums, g1, be1, ss);

    // Layer 2 (commuted): A2 = agg(h1) (D=128) + svec; h2 = relu((ss*A2 + ss'*svec) @ W2 + b2)
    k_agg2<128, true, false><<<AB, 256, 0, stream>>>(hb, col, basep, deg, dinv, nullptr, mb, svec);
    k_gemm_bf<128, 2, 2, 2, true><<<dim3(GBM, 2), 256, 0, stream>>>(mb, Wt2, ss, svec, b2, hb, 128, 256);
    hipMemsetAsync(sums, 0, 512 * 4, stream);
    k_bnstats2<256, false><<<512, 256, 0, stream>>>(hb, sums);
    k_bnfin<256><<<1, 256, 0, stream>>>(sums, g2, be2, ss);

    // Layer 3: (affine h2) @ W3 -> m3(128); agg+b3+relu -> h3(hb); BN3 stats
    k_gemm_bf<128, 2, 2, 1, false><<<dim3(GBM, 1), 256, 0, stream>>>(hb, Wt3, ss, nullptr, nullptr, mb, 256, 128);
    k_agg2<128, false, false><<<AB, 256, 0, stream>>>(mb, col, basep, deg, dinv, b3, hb, nullptr);
    hipMemsetAsync(sums, 0, 512 * 4, stream);
    k_bnstats2<128, false><<<512, 128, 0, stream>>>(hb, sums);
    k_bnfin<128><<<1, 128, 0, stream>>>(sums, g3, be3, ss);

    // Layer 4: (affine h3) @ W4 -> m4(64); agg+b4+relu -> out4(f32); BN4; classifier
    k_gemm_bf<64, 4, 1, 1, false><<<dim3(GBM, 1), 256, 0, stream>>>(hb, Wt4, ss, nullptr, nullptr, mb, 128, 64);
    k_agg2<64, false, true><<<AB, 256, 0, stream>>>(mb, col, basep, deg, dinv, b4, out4, nullptr);
    hipMemsetAsync(sums, 0, 512 * 4, stream);
    k_bnstats2<64, true><<<512, 64, 0, stream>>>(out4, sums);
    k_bnfin<64><<<1, 64, 0, stream>>>(sums, g4, be4, ss);
    k_bnlog<<<(N_NODES * 64 + 255) / 256, 256, 0, stream>>>(out4, ss, Wc, bc, bn4, outLogits);
}

// Round 4
// 788.336 us; speedup vs baseline: 1.7953x; 1.1017x over previous
//
#include <hip/hip_runtime.h>
#include <hip/hip_bf16.h>

#define N_NODES 100000
#define N_EDGES 1600000
#define NB ((N_NODES + 255) / 256)          // 391 dst-buckets of 256 nodes
#define CHUNK 16384
#define NBLK ((N_EDGES + CHUNK - 1) / CHUNK) // 98 partition blocks

typedef short sh8 __attribute__((ext_vector_type(8)));
typedef float f32x4 __attribute__((ext_vector_type(4)));

__device__ __forceinline__ float bf2f(unsigned short s) {
    return __uint_as_float(((unsigned int)s) << 16);
}
__device__ __forceinline__ unsigned short f2bf(float f) {
    unsigned int u = __float_as_uint(f);
    unsigned int r = (u + 0x7FFFu + ((u >> 16) & 1u)) >> 16;
    return (unsigned short)r;
}
__device__ __forceinline__ float blo(unsigned int u) { return __uint_as_float(u << 16); }
__device__ __forceinline__ float bhi(unsigned int u) { return __uint_as_float(u & 0xffff0000u); }

// ---------------- graph preprocessing: partition + bucket sort -> CSR ----------------

// Pass A: per-block histogram over 391 buckets
__global__ __launch_bounds__(256) void k_hist(const int* __restrict__ ei, int* __restrict__ histG) {
    __shared__ int hist[NB];
    int blk = blockIdx.x, t = threadIdx.x;
    for (int b = t; b < NB; b += 256) hist[b] = 0;
    __syncthreads();
    int e0 = blk * CHUNK;
    int e1 = min(e0 + CHUNK, N_EDGES);
    for (int e = e0 + t; e < e1; e += 256) atomicAdd(&hist[ei[N_EDGES + e] >> 8], 1);
    __syncthreads();
    for (int b = t; b < NB; b += 256) histG[b * NBLK + blk] = hist[b];
}

// Scan within each bucket-row over blocks; emit per-bucket totals
__global__ __launch_bounds__(128) void k_scanrow(int* __restrict__ histG, int* __restrict__ rowsum) {
    __shared__ int sm[128];
    int b = blockIdx.x, t = threadIdx.x;
    int v = (t < NBLK) ? histG[b * NBLK + t] : 0;
    sm[t] = v; __syncthreads();
    for (int d = 1; d < 128; d <<= 1) {
        int add = (t >= d) ? sm[t - d] : 0;
        __syncthreads(); sm[t] += add; __syncthreads();
    }
    if (t < NBLK) histG[b * NBLK + t] = sm[t] - v; // exclusive within row
    if (t == 127) rowsum[b] = sm[127];
}

// Scan bucket totals -> rowbase[NB+1]
__global__ __launch_bounds__(512) void k_scanbkt(const int* __restrict__ rowsum, int* __restrict__ rowbase) {
    __shared__ int sm[512];
    int t = threadIdx.x;
    int v = (t < NB) ? rowsum[t] : 0;
    sm[t] = v; __syncthreads();
    for (int d = 1; d < 512; d <<= 1) {
        int add = (t >= d) ? sm[t - d] : 0;
        __syncthreads(); sm[t] += add; __syncthreads();
    }
    if (t <= NB) rowbase[t] = sm[t] - v; // exclusive; rowbase[NB]=N_EDGES
}

// Pass B: contiguous per-(block,bucket) writes of packed pairs (src<<8 | dst&255)
__global__ __launch_bounds__(256) void k_part(const int* __restrict__ ei, const int* __restrict__ histG,
                                              const int* __restrict__ rowbase, unsigned* __restrict__ pairs) {
    __shared__ int cur[NB];
    int blk = blockIdx.x, t = threadIdx.x;
    for (int b = t; b < NB; b += 256) cur[b] = rowbase[b] + histG[b * NBLK + blk];
    __syncthreads();
    int e0 = blk * CHUNK;
    int e1 = min(e0 + CHUNK, N_EDGES);
    for (int e = e0 + t; e < e1; e += 256) {
        int s = ei[e], d = ei[N_EDGES + e];
        int pos = atomicAdd(&cur[d >> 8], 1);
        pairs[pos] = ((unsigned)s << 8) | (unsigned)(d & 255);
    }
}

// Within-bucket counting sort -> col, basep, deg, dinv, sdeg
__global__ __launch_bounds__(256) void k_bsort(const unsigned* __restrict__ pairs, const int* __restrict__ rowbase,
                                               int* __restrict__ col, int* __restrict__ basep,
                                               int* __restrict__ deg, float* __restrict__ dinv,
                                               float* __restrict__ sdeg) {
    __shared__ int cnt[256];
    __shared__ int sm[256];
    __shared__ int cur[256];
    int b = blockIdx.x, t = threadIdx.x;
    int base = rowbase[b], end = rowbase[b + 1];
    cnt[t] = 0; __syncthreads();
    for (int e = base + t; e < end; e += 256) atomicAdd(&cnt[pairs[e] & 255], 1);
    __syncthreads();
    int v = cnt[t];
    sm[t] = v; __syncthreads();
    for (int d = 1; d < 256; d <<= 1) {
        int add = (t >= d) ? sm[t - d] : 0;
        __syncthreads(); sm[t] += add; __syncthreads();
    }
    int excl = sm[t] - v;
    cur[t] = excl;
    int gd = (b << 8) + t;
    if (gd < N_NODES) {
        basep[gd] = base + excl;
        deg[gd] = v;
        dinv[gd] = rsqrtf((float)(v + 1));
        sdeg[gd] = sqrtf((float)(v + 1));
    }
    __syncthreads();
    for (int e = base + t; e < end; e += 256) {
        unsigned p = pairs[e];
        int pos = atomicAdd(&cur[p & 255], 1);
        col[base + pos] = (int)(p >> 8);
    }
}

// svec[w] = dinv[w]*(sum_e dinv[src] + dinv[w])  (graph-only, once)
__global__ __launch_bounds__(256) void k_svec(const int* __restrict__ col, const int* __restrict__ basep,
                                              const int* __restrict__ deg, const float* __restrict__ dinv,
                                              float* __restrict__ svec) {
    int w = (blockIdx.x * 256 + threadIdx.x) >> 6;
    if (w >= N_NODES) return;
    int lane = threadIdx.x & 63;
    int start = basep[w], cnt = deg[w];
    float s = 0.f;
    for (int j = lane; j < cnt; j += 64) s += dinv[col[start + j]];
#pragma unroll
    for (int off = 32; off; off >>= 1) s += __shfl_down(s, off, 64);
    if (lane == 0) { float di = dinv[w]; svec[w] = di * (s + di); }
}

// ---------------- W transpose + bf16 convert ----------------

__global__ void k_wconv(const float* __restrict__ W, unsigned short* __restrict__ Wt, int K, int N) {
    int idx = blockIdx.x * 256 + threadIdx.x;
    if (idx >= K * N) return;
    int n = idx / K, k = idx - n * K;
    Wt[idx] = f2bf(W[(size_t)k * N + n]);
}

// ---------------- bf16 MFMA GEMM ----------------
// AMODE: 0=f32 plain; 1=bf16 affine ss; 2=bf16 affine ss + ss'*svec[row]
// BIASRELU: out=relu(acc+bias[col]);  DSCALE: out *= dinv[row] (message scaling)

template <int BN, int NWM, int NWN, int AMODE, bool BIASRELU, bool DSCALE>
__global__ __launch_bounds__(256) void k_gemm_bf(const void* __restrict__ Ain,
                                                 const unsigned short* __restrict__ Wt,
                                                 const float* __restrict__ ss,
                                                 const float* __restrict__ svec,
                                                 const float* __restrict__ bias,
                                                 const float* __restrict__ dinv,
                                                 unsigned short* __restrict__ Mout,
                                                 int K, int NTOT) {
    constexpr int BK = 64;
    constexpr int LDA = BK + 8;
    constexpr int MF = 128 / (16 * NWM);
    constexpr int NF = BN / (16 * NWN);
    __shared__ unsigned short As[128 * LDA];
    __shared__ unsigned short Bs[BN * LDA];
    const int tid = threadIdx.x;
    const int lane = tid & 63;
    const int w = tid >> 6;
    const int wm = w / NWN, wn = w % NWN;
    const int row0 = blockIdx.x * 128;
    const int col0 = blockIdx.y * BN;

    f32x4 acc[MF][NF];
#pragma unroll
    for (int i = 0; i < MF; ++i)
#pragma unroll
        for (int j = 0; j < NF; ++j)
#pragma unroll
            for (int r = 0; r < 4; ++r) acc[i][j][r] = 0.f;

    const int sr = tid >> 3;        // 0..31
    const int scc = (tid & 7) * 8;  // 0..56

    for (int k0 = 0; k0 < K; k0 += BK) {
#pragma unroll
        for (int p = 0; p < 4; ++p) {
            int r = p * 32 + sr;
            int gr = row0 + r;
            alignas(16) unsigned short tmp[8];
            if constexpr (AMODE == 0) {
                const float* Af = (const float*)Ain;
                float4 v0 = make_float4(0.f, 0.f, 0.f, 0.f), v1 = v0;
                if (gr < N_NODES) {
                    const float* p0 = Af + (size_t)gr * K + k0 + scc;
                    v0 = *(const float4*)p0;
                    v1 = *(const float4*)(p0 + 4);
                }
                tmp[0] = f2bf(v0.x); tmp[1] = f2bf(v0.y); tmp[2] = f2bf(v0.z); tmp[3] = f2bf(v0.w);
                tmp[4] = f2bf(v1.x); tmp[5] = f2bf(v1.y); tmp[6] = f2bf(v1.z); tmp[7] = f2bf(v1.w);
            } else {
                const unsigned short* Ab = (const unsigned short*)Ain;
                uint4 raw = make_uint4(0, 0, 0, 0);
                if (gr < N_NODES) raw = *(const uint4*)(Ab + (size_t)gr * K + k0 + scc);
                const unsigned short* pr = (const unsigned short*)&raw;
                float sv = 1.f;
                if constexpr (AMODE == 2) sv = (gr < N_NODES) ? svec[gr] : 0.f;
#pragma unroll
                for (int q = 0; q < 8; ++q) {
                    float sc = ss[k0 + scc + q];
                    float sh = ss[256 + k0 + scc + q];
                    float val;
                    if constexpr (AMODE == 2) val = bf2f(pr[q]) * sc + sh * sv;
                    else val = bf2f(pr[q]) * sc + sh;
                    tmp[q] = f2bf(val);
                }
            }
            *(uint4*)&As[r * LDA + scc] = *(const uint4*)tmp;
        }
        constexpr int BP = (BN * BK) / 2048;
#pragma unroll
        for (int p = 0; p < BP; ++p) {
            int r = p * 32 + sr;
            uint4 raw = *(const uint4*)(Wt + (size_t)(col0 + r) * K + k0 + scc);
            *(uint4*)&Bs[r * LDA + scc] = raw;
        }
        __syncthreads();
#pragma unroll
        for (int ks = 0; ks < 2; ++ks) {
            sh8 af[MF], bfr[NF];
#pragma unroll
            for (int i = 0; i < MF; ++i)
                af[i] = *(const sh8*)&As[(wm * MF * 16 + i * 16 + (lane & 15)) * LDA + ks * 32 + (lane >> 4) * 8];
#pragma unroll
            for (int j = 0; j < NF; ++j)
                bfr[j] = *(const sh8*)&Bs[(wn * NF * 16 + j * 16 + (lane & 15)) * LDA + ks * 32 + (lane >> 4) * 8];
#pragma unroll
            for (int i = 0; i < MF; ++i)
#pragma unroll
                for (int j = 0; j < NF; ++j)
                    acc[i][j] = __builtin_amdgcn_mfma_f32_16x16x32_bf16(af[i], bfr[j], acc[i][j], 0, 0, 0);
        }
        __syncthreads();
    }
#pragma unroll
    for (int i = 0; i < MF; ++i) {
#pragma unroll
        for (int r = 0; r < 4; ++r) {
            int grow = row0 + wm * MF * 16 + i * 16 + (lane >> 4) * 4 + r;
            if (grow >= N_NODES) continue;
            float rsc = 1.f;
            if constexpr (DSCALE) rsc = dinv[grow];
#pragma unroll
            for (int j = 0; j < NF; ++j) {
                int gcol = col0 + wn * NF * 16 + j * 16 + (lane & 15);
                float v = acc[i][j][r];
                if constexpr (BIASRELU) v = fmaxf(v + bias[gcol], 0.f);
                if constexpr (DSCALE) v *= rsc;
                Mout[(size_t)grow * NTOT + gcol] = f2bf(v);
            }
        }
    }
}

// ---------------- aggregation (wave per node, unroll-8, pre-scaled messages) ----------------
// acc = sum_edges m'[src] + m'[self]
// POST: out = relu(di*acc + bias) [*di if OUTSCALE];  PRE: out = di*acc

template <int D, bool PRE, bool OUTF32, bool OUTSCALE>
__global__ __launch_bounds__(256) void k_agg3(const unsigned short* __restrict__ m,
                                              const int* __restrict__ col,
                                              const int* __restrict__ basep,
                                              const int* __restrict__ deg,
                                              const float* __restrict__ dinv,
                                              const float* __restrict__ bias,
                                              void* __restrict__ out) {
    constexpr int VPL = D / 64;
    int w = (blockIdx.x * 256 + threadIdx.x) >> 6;
    if (w >= N_NODES) return;
    int lane = threadIdx.x & 63;
    int fo = lane * VPL;
    const unsigned short* mfo = m + fo;
    float acc[VPL];
#pragma unroll
    for (int k = 0; k < VPL; ++k) acc[k] = 0.f;

    int start = basep[w], cnt = deg[w];
    int j = 0;
    for (; j + 8 <= cnt; j += 8) {
        int sx[8];
#pragma unroll
        for (int i = 0; i < 8; ++i) sx[i] = col[start + j + i];
        if constexpr (VPL == 2) {
            unsigned u[8];
#pragma unroll
            for (int i = 0; i < 8; ++i) u[i] = *(const unsigned*)(mfo + (size_t)sx[i] * D);
#pragma unroll
            for (int i = 0; i < 8; ++i) { acc[0] += blo(u[i]); acc[1] += bhi(u[i]); }
        } else {
            float v[8];
#pragma unroll
            for (int i = 0; i < 8; ++i) v[i] = bf2f(mfo[(size_t)sx[i] * D]);
#pragma unroll
            for (int i = 0; i < 8; ++i) acc[0] += v[i];
        }
    }
    for (; j < cnt; ++j) {
        int s0 = col[start + j];
        if constexpr (VPL == 2) {
            unsigned u0 = *(const unsigned*)(mfo + (size_t)s0 * D);
            acc[0] += blo(u0); acc[1] += bhi(u0);
        } else {
            acc[0] += bf2f(mfo[(size_t)s0 * D]);
        }
    }
    // self
    if constexpr (VPL == 2) {
        unsigned u0 = *(const unsigned*)(mfo + (size_t)w * D);
        acc[0] += blo(u0); acc[1] += bhi(u0);
    } else {
        acc[0] += bf2f(mfo[(size_t)w * D]);
    }

    float di = dinv[w];
    float o[VPL];
    if constexpr (PRE) {
#pragma unroll
        for (int k = 0; k < VPL; ++k) o[k] = acc[k] * di;
    } else {
#pragma unroll
        for (int k = 0; k < VPL; ++k) {
            o[k] = fmaxf(acc[k] * di + bias[fo + k], 0.f);
            if constexpr (OUTSCALE) o[k] *= di;
        }
    }

    if constexpr (OUTF32) {
        float* of = (float*)out;
#pragma unroll
        for (int k = 0; k < VPL; ++k) of[(size_t)w * D + fo + k] = o[k];
    } else {
        unsigned short* ob = (unsigned short*)out + (size_t)w * D + fo;
        if constexpr (VPL == 2) {
            unsigned int u = (unsigned)f2bf(o[0]) | ((unsigned)f2bf(o[1]) << 16);
            *(unsigned int*)ob = u;
        } else {
            ob[0] = f2bf(o[0]);
        }
    }
}

// ---------------- BatchNorm stats / finalize ----------------

template <int D, bool INF32, bool RESCALE>
__global__ void k_bnstats3(const void* __restrict__ h, const float* __restrict__ sdeg,
                           float* __restrict__ sums) {
    int f = threadIdx.x; // blockDim == D
    float s = 0.f, s2 = 0.f;
    for (int r = blockIdx.x; r < N_NODES; r += gridDim.x) {
        float v;
        if constexpr (INF32) v = ((const float*)h)[(size_t)r * D + f];
        else v = bf2f(((const unsigned short*)h)[(size_t)r * D + f]);
        if constexpr (RESCALE) v *= sdeg[r];
        s += v; s2 += v * v;
    }
    atomicAdd(&sums[f], s);
    atomicAdd(&sums[256 + f], s2);
}

template <int D>
__global__ void k_bnfin(const float* __restrict__ sums, const float* __restrict__ gamma,
                        const float* __restrict__ beta, float* __restrict__ ss) {
    int f = threadIdx.x; // blockDim == D
    float mean = sums[f] * (1.f / N_NODES);
    float var = sums[256 + f] * (1.f / N_NODES) - mean * mean;
    float inv = rsqrtf(var + 1e-5f);
    float sc = gamma[f] * inv;
    ss[f] = sc;
    ss[256 + f] = beta[f] - mean * sc;
}

// ---------------- layer-4 BN apply + classifier ----------------

__global__ __launch_bounds__(256) void k_bnlog(const float* __restrict__ out4, const float* __restrict__ ss,
                                               const float* __restrict__ Wc, const float* __restrict__ bc,
                                               float* __restrict__ bn4, float* __restrict__ logits) {
    int gw = (blockIdx.x * 256 + threadIdx.x) >> 6;
    if (gw >= N_NODES) return;
    int f = threadIdx.x & 63;
    float v = out4[(size_t)gw * 64 + f];
    float bn = v * ss[f] + ss[256 + f];
    bn4[(size_t)gw * 64 + f] = bn;
    float a0 = bn * Wc[2 * f];
    float a1 = bn * Wc[2 * f + 1];
#pragma unroll
    for (int off = 32; off; off >>= 1) {
        a0 += __shfl_down(a0, off, 64);
        a1 += __shfl_down(a1, off, 64);
    }
    if (f == 0) {
        logits[2 * gw] = a0 + bc[0];
        logits[2 * gw + 1] = a1 + bc[1];
    }
}

// ---------------- launch ----------------

extern "C" void kernel_launch(void* const* d_in, const int* in_sizes, int n_in,
                              void* d_out, int out_size, void* d_ws, size_t ws_size,
                              hipStream_t stream) {
    const float* x  = (const float*)d_in[0];
    const int* ei   = (const int*)d_in[1];
    const float* W1 = (const float*)d_in[2];  const float* b1  = (const float*)d_in[3];
    const float* W2 = (const float*)d_in[4];  const float* b2  = (const float*)d_in[5];
    const float* W3 = (const float*)d_in[6];  const float* b3  = (const float*)d_in[7];
    const float* W4 = (const float*)d_in[8];  const float* b4  = (const float*)d_in[9];
    const float* Wc = (const float*)d_in[10]; const float* bc  = (const float*)d_in[11];
    const float* g1 = (const float*)d_in[12]; const float* be1 = (const float*)d_in[13];
    const float* g2 = (const float*)d_in[14]; const float* be2 = (const float*)d_in[15];
    const float* g3 = (const float*)d_in[16]; const float* be3 = (const float*)d_in[17];
    const float* g4 = (const float*)d_in[18]; const float* be4 = (const float*)d_in[19];

    char* wsb = (char*)d_ws;
    size_t off = 0;
    auto alloc = [&](size_t bytes) -> void* {
        void* p = wsb + off;
        off = (off + bytes + 511) & ~(size_t)511;
        return p;
    };
    int* deg     = (int*)alloc((size_t)N_NODES * 4);
    int* basep   = (int*)alloc((size_t)N_NODES * 4);
    float* dinv  = (float*)alloc((size_t)N_NODES * 4);
    float* sdeg  = (float*)alloc((size_t)N_NODES * 4);
    float* svec  = (float*)alloc((size_t)N_NODES * 4);
    int* col     = (int*)alloc((size_t)N_EDGES * 4);
    unsigned* pairs = (unsigned*)alloc((size_t)N_EDGES * 4);
    int* histG   = (int*)alloc((size_t)NB * NBLK * 4);
    int* rowsum  = (int*)alloc((size_t)NB * 4);
    int* rowbase = (int*)alloc((size_t)(NB + 1) * 4);
    float* sums  = (float*)alloc(512 * 4);
    float* ss    = (float*)alloc(512 * 4);
    unsigned short* Wt1 = (unsigned short*)alloc((size_t)256 * 128 * 2);
    unsigned short* Wt2 = (unsigned short*)alloc((size_t)128 * 256 * 2);
    unsigned short* Wt3 = (unsigned short*)alloc((size_t)256 * 128 * 2);
    unsigned short* Wt4 = (unsigned short*)alloc((size_t)128 * 64 * 2);
    unsigned short* mb = (unsigned short*)alloc((size_t)N_NODES * 128 * 2);
    unsigned short* hb = (unsigned short*)alloc((size_t)N_NODES * 256 * 2);

    float* outLogits = (float*)d_out;
    float* out4 = outLogits + (size_t)N_NODES * 2;
    float* bn4  = out4 + (size_t)N_NODES * 64;

    // ---- CSR build: partition + bucket sort ----
    k_hist<<<NBLK, 256, 0, stream>>>(ei, histG);
    k_scanrow<<<NB, 128, 0, stream>>>(histG, rowsum);
    k_scanbkt<<<1, 512, 0, stream>>>(rowsum, rowbase);
    k_part<<<NBLK, 256, 0, stream>>>(ei, histG, rowbase, pairs);
    k_bsort<<<NB, 256, 0, stream>>>(pairs, rowbase, col, basep, deg, dinv, sdeg);
    k_svec<<<(N_NODES + 3) / 4, 256, 0, stream>>>(col, basep, deg, dinv, svec);

    k_wconv<<<(256 * 128 + 255) / 256, 256, 0, stream>>>(W1, Wt1, 256, 128);
    k_wconv<<<(128 * 256 + 255) / 256, 256, 0, stream>>>(W2, Wt2, 128, 256);
    k_wconv<<<(256 * 128 + 255) / 256, 256, 0, stream>>>(W3, Wt3, 256, 128);
    k_wconv<<<(128 * 64 + 255) / 256, 256, 0, stream>>>(W4, Wt4, 128, 64);

    const int GBM = (N_NODES + 127) / 128; // 782
    const int AB = (N_NODES + 3) / 4;      // wave per node

    // Layer 1: m1' = dinv*(x @ W1); agg -> q1 = dinv*relu(...); BN1 stats (rescaled)
    k_gemm_bf<128, 2, 2, 0, false, true><<<dim3(GBM, 1), 256, 0, stream>>>(x, Wt1, nullptr, nullptr, nullptr, dinv, mb, 256, 128);
    k_agg3<128, false, false, true><<<AB, 256, 0, stream>>>(mb, col, basep, deg, dinv, b1, hb);
    hipMemsetAsync(sums, 0, 512 * 4, stream);
    k_bnstats3<128, false, true><<<512, 128, 0, stream>>>(hb, sdeg, sums);
    k_bnfin<128><<<1, 128, 0, stream>>>(sums, g1, be1, ss);

    // Layer 2 (commuted): A2 = di*(sum q1); h2 = relu((ss*A2 + ss'*svec) @ W2 + b2)
    k_agg3<128, true, false, false><<<AB, 256, 0, stream>>>(hb, col, basep, deg, dinv, nullptr, mb);
    k_gemm_bf<128, 2, 2, 2, true, false><<<dim3(GBM, 2), 256, 0, stream>>>(mb, Wt2, ss, svec, b2, nullptr, hb, 128, 256);
    hipMemsetAsync(sums, 0, 512 * 4, stream);
    k_bnstats3<256, false, false><<<512, 256, 0, stream>>>(hb, nullptr, sums);
    k_bnfin<256><<<1, 256, 0, stream>>>(sums, g2, be2, ss);

    // Layer 3: m3' = dinv*(affine(h2) @ W3); agg+b3+relu -> h3; BN3 stats
    k_gemm_bf<128, 2, 2, 1, false, true><<<dim3(GBM, 1), 256, 0, stream>>>(hb, Wt3, ss, nullptr, nullptr, dinv, mb, 256, 128);
    k_agg3<128, false, false, false><<<AB, 256, 0, stream>>>(mb, col, basep, deg, dinv, b3, hb);
    hipMemsetAsync(sums, 0, 512 * 4, stream);
    k_bnstats3<128, false, false><<<512, 128, 0, stream>>>(hb, nullptr, sums);
    k_bnfin<128><<<1, 128, 0, stream>>>(sums, g3, be3, ss);

    // Layer 4: m4' = dinv*(affine(h3) @ W4); agg+b4+relu -> out4 (f32); BN4; classifier
    k_gemm_bf<64, 4, 1, 1, false, true><<<dim3(GBM, 1), 256, 0, stream>>>(hb, Wt4, ss, nullptr, nullptr, dinv, mb, 128, 64);
    k_agg3<64, false, true, false><<<AB, 256, 0, stream>>>(mb, col, basep, deg, dinv, b4, out4);
    hipMemsetAsync(sums, 0, 512 * 4, stream);
    k_bnstats3<64, true, false><<<512, 64, 0, stream>>>(out4, nullptr, sums);
    k_bnfin<64><<<1, 64, 0, stream>>>(sums, g4, be4, ss);
    k_bnlog<<<(N_NODES * 64 + 255) / 256, 256, 0, stream>>>(out4, ss, Wc, bc, bn4, outLogits);
}

// Round 5
// 703.464 us; speedup vs baseline: 2.0119x; 1.1206x over previous
//
#include <hip/hip_runtime.h>
#include <hip/hip_bf16.h>

#define N_NODES 100000
#define N_EDGES 1600000
#define NB ((N_NODES + 255) / 256)          // 391 dst-buckets of 256 nodes
#define CHUNK 16384
#define NBLK ((N_EDGES + CHUNK - 1) / CHUNK) // 98 partition blocks

typedef short sh8 __attribute__((ext_vector_type(8)));
typedef float f32x4 __attribute__((ext_vector_type(4)));

__device__ __forceinline__ float bf2f(unsigned short s) {
    return __uint_as_float(((unsigned int)s) << 16);
}
__device__ __forceinline__ unsigned short f2bf(float f) {
    unsigned int u = __float_as_uint(f);
    unsigned int r = (u + 0x7FFFu + ((u >> 16) & 1u)) >> 16;
    return (unsigned short)r;
}
__device__ __forceinline__ float blo(unsigned int u) { return __uint_as_float(u << 16); }
__device__ __forceinline__ float bhi(unsigned int u) { return __uint_as_float(u & 0xffff0000u); }

// ---------------- graph preprocessing: partition + bucket sort -> CSR ----------------

__global__ __launch_bounds__(256) void k_hist(const int* __restrict__ ei, int* __restrict__ histG) {
    __shared__ int hist[NB];
    int blk = blockIdx.x, t = threadIdx.x;
    for (int b = t; b < NB; b += 256) hist[b] = 0;
    __syncthreads();
    int e0 = blk * CHUNK;
    int e1 = min(e0 + CHUNK, N_EDGES);
    for (int e = e0 + t; e < e1; e += 256) atomicAdd(&hist[ei[N_EDGES + e] >> 8], 1);
    __syncthreads();
    for (int b = t; b < NB; b += 256) histG[b * NBLK + blk] = hist[b];
}

__global__ __launch_bounds__(128) void k_scanrow(int* __restrict__ histG, int* __restrict__ rowsum) {
    __shared__ int sm[128];
    int b = blockIdx.x, t = threadIdx.x;
    int v = (t < NBLK) ? histG[b * NBLK + t] : 0;
    sm[t] = v; __syncthreads();
    for (int d = 1; d < 128; d <<= 1) {
        int add = (t >= d) ? sm[t - d] : 0;
        __syncthreads(); sm[t] += add; __syncthreads();
    }
    if (t < NBLK) histG[b * NBLK + t] = sm[t] - v;
    if (t == 127) rowsum[b] = sm[127];
}

__global__ __launch_bounds__(512) void k_scanbkt(const int* __restrict__ rowsum, int* __restrict__ rowbase) {
    __shared__ int sm[512];
    int t = threadIdx.x;
    int v = (t < NB) ? rowsum[t] : 0;
    sm[t] = v; __syncthreads();
    for (int d = 1; d < 512; d <<= 1) {
        int add = (t >= d) ? sm[t - d] : 0;
        __syncthreads(); sm[t] += add; __syncthreads();
    }
    if (t <= NB) rowbase[t] = sm[t] - v;
}

__global__ __launch_bounds__(256) void k_part(const int* __restrict__ ei, const int* __restrict__ histG,
                                              const int* __restrict__ rowbase, unsigned* __restrict__ pairs) {
    __shared__ int cur[NB];
    int blk = blockIdx.x, t = threadIdx.x;
    for (int b = t; b < NB; b += 256) cur[b] = rowbase[b] + histG[b * NBLK + blk];
    __syncthreads();
    int e0 = blk * CHUNK;
    int e1 = min(e0 + CHUNK, N_EDGES);
    for (int e = e0 + t; e < e1; e += 256) {
        int s = ei[e], d = ei[N_EDGES + e];
        int pos = atomicAdd(&cur[d >> 8], 1);
        pairs[pos] = ((unsigned)s << 8) | (unsigned)(d & 255);
    }
}

__global__ __launch_bounds__(256) void k_bsort(const unsigned* __restrict__ pairs, const int* __restrict__ rowbase,
                                               int* __restrict__ col, int* __restrict__ basep,
                                               int* __restrict__ deg, float* __restrict__ dinv,
                                               float* __restrict__ sdeg) {
    __shared__ int cnt[256];
    __shared__ int sm[256];
    __shared__ int cur[256];
    int b = blockIdx.x, t = threadIdx.x;
    int base = rowbase[b], end = rowbase[b + 1];
    cnt[t] = 0; __syncthreads();
    for (int e = base + t; e < end; e += 256) atomicAdd(&cnt[pairs[e] & 255], 1);
    __syncthreads();
    int v = cnt[t];
    sm[t] = v; __syncthreads();
    for (int d = 1; d < 256; d <<= 1) {
        int add = (t >= d) ? sm[t - d] : 0;
        __syncthreads(); sm[t] += add; __syncthreads();
    }
    int excl = sm[t] - v;
    cur[t] = excl;
    int gd = (b << 8) + t;
    if (gd < N_NODES) {
        basep[gd] = base + excl;
        deg[gd] = v;
        dinv[gd] = rsqrtf((float)(v + 1));
        sdeg[gd] = sqrtf((float)(v + 1));
    }
    __syncthreads();
    for (int e = base + t; e < end; e += 256) {
        unsigned p = pairs[e];
        int pos = atomicAdd(&cur[p & 255], 1);
        col[base + pos] = (int)(p >> 8);
    }
}

// svec[w] = dinv[w]*(sum_e dinv[src] + dinv[w])
__global__ __launch_bounds__(256) void k_svec(const int* __restrict__ col, const int* __restrict__ basep,
                                              const int* __restrict__ deg, const float* __restrict__ dinv,
                                              float* __restrict__ svec) {
    int w = (blockIdx.x * 256 + threadIdx.x) >> 6;
    if (w >= N_NODES) return;
    int lane = threadIdx.x & 63;
    int start = basep[w], cnt = deg[w];
    float s = 0.f;
    for (int j = lane; j < cnt; j += 64) s += dinv[col[start + j]];
#pragma unroll
    for (int off = 32; off; off >>= 1) s += __shfl_down(s, off, 64);
    if (lane == 0) { float di = dinv[w]; svec[w] = di * (s + di); }
}

// ---------------- all W transpose + bf16 convert in one dispatch ----------------

__global__ void k_wconv_all(const float* __restrict__ W1, const float* __restrict__ W2,
                            const float* __restrict__ W3, const float* __restrict__ W4,
                            unsigned short* __restrict__ Wt1, unsigned short* __restrict__ Wt2,
                            unsigned short* __restrict__ Wt3, unsigned short* __restrict__ Wt4) {
    int idx = blockIdx.x * 256 + threadIdx.x;
    const float* W; unsigned short* Wt; int K, N, base;
    if (idx < 32768)       { W = W1; Wt = Wt1; K = 256; N = 128; base = 0; }
    else if (idx < 65536)  { W = W2; Wt = Wt2; K = 128; N = 256; base = 32768; }
    else if (idx < 98304)  { W = W3; Wt = Wt3; K = 256; N = 128; base = 65536; }
    else if (idx < 106496) { W = W4; Wt = Wt4; K = 128; N = 64;  base = 98304; }
    else return;
    int li = idx - base;
    int n = li / K, k = li - n * K;
    Wt[li] = f2bf(W[(size_t)k * N + n]);
}

// ---------------- bf16 MFMA GEMM ----------------
// AMODE: 0=f32 plain; 1=bf16 affine ss; 2=bf16 affine ss + ss'*svec[row]
// BIASRELU: out=relu(acc+bias[col]); DSCALE: out *= dinv[row]; STATS: fused BN sums over output cols

template <int BN, int NWM, int NWN, int AMODE, bool BIASRELU, bool DSCALE, bool STATS>
__global__ __launch_bounds__(256) void k_gemm_bf(const void* __restrict__ Ain,
                                                 const unsigned short* __restrict__ Wt,
                                                 const float* __restrict__ ss,
                                                 const float* __restrict__ svec,
                                                 const float* __restrict__ bias,
                                                 const float* __restrict__ dinv,
                                                 unsigned short* __restrict__ Mout,
                                                 float* __restrict__ sums,
                                                 int K, int NTOT) {
    constexpr int BK = 64;
    constexpr int LDA = BK + 8;
    constexpr int MF = 128 / (16 * NWM);
    constexpr int NF = BN / (16 * NWN);
    __shared__ unsigned short As[128 * LDA];
    __shared__ unsigned short Bs[BN * LDA];
    const int tid = threadIdx.x;
    const int lane = tid & 63;
    const int w = tid >> 6;
    const int wm = w / NWN, wn = w % NWN;
    const int row0 = blockIdx.x * 128;
    const int col0 = blockIdx.y * BN;

    f32x4 acc[MF][NF];
#pragma unroll
    for (int i = 0; i < MF; ++i)
#pragma unroll
        for (int j = 0; j < NF; ++j)
#pragma unroll
            for (int r = 0; r < 4; ++r) acc[i][j][r] = 0.f;

    const int sr = tid >> 3;        // 0..31
    const int scc = (tid & 7) * 8;  // 0..56

    for (int k0 = 0; k0 < K; k0 += BK) {
#pragma unroll
        for (int p = 0; p < 4; ++p) {
            int r = p * 32 + sr;
            int gr = row0 + r;
            alignas(16) unsigned short tmp[8];
            if constexpr (AMODE == 0) {
                const float* Af = (const float*)Ain;
                float4 v0 = make_float4(0.f, 0.f, 0.f, 0.f), v1 = v0;
                if (gr < N_NODES) {
                    const float* p0 = Af + (size_t)gr * K + k0 + scc;
                    v0 = *(const float4*)p0;
                    v1 = *(const float4*)(p0 + 4);
                }
                tmp[0] = f2bf(v0.x); tmp[1] = f2bf(v0.y); tmp[2] = f2bf(v0.z); tmp[3] = f2bf(v0.w);
                tmp[4] = f2bf(v1.x); tmp[5] = f2bf(v1.y); tmp[6] = f2bf(v1.z); tmp[7] = f2bf(v1.w);
            } else {
                const unsigned short* Ab = (const unsigned short*)Ain;
                uint4 raw = make_uint4(0, 0, 0, 0);
                if (gr < N_NODES) raw = *(const uint4*)(Ab + (size_t)gr * K + k0 + scc);
                const unsigned short* pr = (const unsigned short*)&raw;
                float sv = 1.f;
                if constexpr (AMODE == 2) sv = (gr < N_NODES) ? svec[gr] : 0.f;
#pragma unroll
                for (int q = 0; q < 8; ++q) {
                    float sc = ss[k0 + scc + q];
                    float sh = ss[256 + k0 + scc + q];
                    float val;
                    if constexpr (AMODE == 2) val = bf2f(pr[q]) * sc + sh * sv;
                    else val = bf2f(pr[q]) * sc + sh;
                    tmp[q] = f2bf(val);
                }
            }
            *(uint4*)&As[r * LDA + scc] = *(const uint4*)tmp;
        }
        constexpr int BP = (BN * BK) / 2048;
#pragma unroll
        for (int p = 0; p < BP; ++p) {
            int r = p * 32 + sr;
            uint4 raw = *(const uint4*)(Wt + (size_t)(col0 + r) * K + k0 + scc);
            *(uint4*)&Bs[r * LDA + scc] = raw;
        }
        __syncthreads();
#pragma unroll
        for (int ks = 0; ks < 2; ++ks) {
            sh8 af[MF], bfr[NF];
#pragma unroll
            for (int i = 0; i < MF; ++i)
                af[i] = *(const sh8*)&As[(wm * MF * 16 + i * 16 + (lane & 15)) * LDA + ks * 32 + (lane >> 4) * 8];
#pragma unroll
            for (int j = 0; j < NF; ++j)
                bfr[j] = *(const sh8*)&Bs[(wn * NF * 16 + j * 16 + (lane & 15)) * LDA + ks * 32 + (lane >> 4) * 8];
#pragma unroll
            for (int i = 0; i < MF; ++i)
#pragma unroll
                for (int j = 0; j < NF; ++j)
                    acc[i][j] = __builtin_amdgcn_mfma_f32_16x16x32_bf16(af[i], bfr[j], acc[i][j], 0, 0, 0);
        }
        __syncthreads();
    }

    float cs[NF], cs2[NF];
    if constexpr (STATS) {
#pragma unroll
        for (int j = 0; j < NF; ++j) { cs[j] = 0.f; cs2[j] = 0.f; }
    }
#pragma unroll
    for (int i = 0; i < MF; ++i) {
#pragma unroll
        for (int r = 0; r < 4; ++r) {
            int grow = row0 + wm * MF * 16 + i * 16 + (lane >> 4) * 4 + r;
            if (grow >= N_NODES) continue;
            float rsc = 1.f;
            if constexpr (DSCALE) rsc = dinv[grow];
#pragma unroll
            for (int j = 0; j < NF; ++j) {
                int gcol = col0 + wn * NF * 16 + j * 16 + (lane & 15);
                float v = acc[i][j][r];
                if constexpr (BIASRELU) v = fmaxf(v + bias[gcol], 0.f);
                if constexpr (DSCALE) v *= rsc;
                if constexpr (STATS) { cs[j] += v; cs2[j] += v * v; }
                Mout[(size_t)grow * NTOT + gcol] = f2bf(v);
            }
        }
    }
    if constexpr (STATS) {
        __shared__ float red[2][BN];
        for (int i = tid; i < 2 * BN; i += 256) ((float*)red)[i] = 0.f;
        __syncthreads();
#pragma unroll
        for (int j = 0; j < NF; ++j) {
            int lc = wn * NF * 16 + j * 16 + (lane & 15);
            atomicAdd(&red[0][lc], cs[j]);
            atomicAdd(&red[1][lc], cs2[j]);
        }
        __syncthreads();
        for (int f = tid; f < BN; f += 256) {
            atomicAdd(&sums[col0 + f], red[0][f]);
            atomicAdd(&sums[256 + col0 + f], red[1][f]);
        }
    }
}

// ---------------- aggregation (64 nodes/block, wave per node, fused BN stats) ----------------
// acc = sum_edges m'[src] + m'[self]
// POST: out = relu(di*acc + bias) [*di if OUTSCALE]; PRE: out = di*acc
// STATS: accumulate BN sums of (out * (RESCALE ? sdeg : 1))

template <int D, bool PRE, bool OUTF32, bool OUTSCALE, bool STATS, bool RESCALE>
__global__ __launch_bounds__(256) void k_agg4(const unsigned short* __restrict__ m,
                                              const int* __restrict__ col,
                                              const int* __restrict__ basep,
                                              const int* __restrict__ deg,
                                              const float* __restrict__ dinv,
                                              const float* __restrict__ sdeg,
                                              const float* __restrict__ bias,
                                              void* __restrict__ out,
                                              float* __restrict__ sums) {
    constexpr int VPL = D / 64;
    const int lane = threadIdx.x & 63;
    const int wid = threadIdx.x >> 6;
    const int fo = lane * VPL;
    const unsigned short* mfo = m + fo;
    float s1r[VPL], s2r[VPL];
    if constexpr (STATS) {
#pragma unroll
        for (int k = 0; k < VPL; ++k) { s1r[k] = 0.f; s2r[k] = 0.f; }
    }

    for (int it = 0; it < 16; ++it) {
        int w = blockIdx.x * 64 + it * 4 + wid;
        if (w >= N_NODES) continue;
        float acc[VPL];
#pragma unroll
        for (int k = 0; k < VPL; ++k) acc[k] = 0.f;

        int start = basep[w], cnt = deg[w];
        int j = 0;
        for (; j + 8 <= cnt; j += 8) {
            int sx[8];
#pragma unroll
            for (int i = 0; i < 8; ++i) sx[i] = col[start + j + i];
            if constexpr (VPL == 2) {
                unsigned u[8];
#pragma unroll
                for (int i = 0; i < 8; ++i) u[i] = *(const unsigned*)(mfo + (size_t)sx[i] * D);
#pragma unroll
                for (int i = 0; i < 8; ++i) { acc[0] += blo(u[i]); acc[1] += bhi(u[i]); }
            } else {
                float v[8];
#pragma unroll
                for (int i = 0; i < 8; ++i) v[i] = bf2f(mfo[(size_t)sx[i] * D]);
#pragma unroll
                for (int i = 0; i < 8; ++i) acc[0] += v[i];
            }
        }
        for (; j < cnt; ++j) {
            int s0 = col[start + j];
            if constexpr (VPL == 2) {
                unsigned u0 = *(const unsigned*)(mfo + (size_t)s0 * D);
                acc[0] += blo(u0); acc[1] += bhi(u0);
            } else {
                acc[0] += bf2f(mfo[(size_t)s0 * D]);
            }
        }
        if constexpr (VPL == 2) {
            unsigned u0 = *(const unsigned*)(mfo + (size_t)w * D);
            acc[0] += blo(u0); acc[1] += bhi(u0);
        } else {
            acc[0] += bf2f(mfo[(size_t)w * D]);
        }

        float di = dinv[w];
        float o[VPL];
        if constexpr (PRE) {
#pragma unroll
            for (int k = 0; k < VPL; ++k) o[k] = acc[k] * di;
        } else {
#pragma unroll
            for (int k = 0; k < VPL; ++k) {
                o[k] = fmaxf(acc[k] * di + bias[fo + k], 0.f);
                if constexpr (OUTSCALE) o[k] *= di;
            }
        }
        if constexpr (STATS) {
            float rs = 1.f;
            if constexpr (RESCALE) rs = sdeg[w];
#pragma unroll
            for (int k = 0; k < VPL; ++k) { float v = o[k] * rs; s1r[k] += v; s2r[k] += v * v; }
        }

        if constexpr (OUTF32) {
            float* of = (float*)out;
#pragma unroll
            for (int k = 0; k < VPL; ++k) of[(size_t)w * D + fo + k] = o[k];
        } else {
            unsigned short* ob = (unsigned short*)out + (size_t)w * D + fo;
            if constexpr (VPL == 2) {
                unsigned int u = (unsigned)f2bf(o[0]) | ((unsigned)f2bf(o[1]) << 16);
                *(unsigned int*)ob = u;
            } else {
                ob[0] = f2bf(o[0]);
            }
        }
    }

    if constexpr (STATS) {
        __shared__ float red[2][D];
        for (int i = threadIdx.x; i < 2 * D; i += 256) ((float*)red)[i] = 0.f;
        __syncthreads();
#pragma unroll
        for (int k = 0; k < VPL; ++k) {
            atomicAdd(&red[0][fo + k], s1r[k]);
            atomicAdd(&red[1][fo + k], s2r[k]);
        }
        __syncthreads();
        for (int f = threadIdx.x; f < D; f += 256) {
            atomicAdd(&sums[f], red[0][f]);
            atomicAdd(&sums[256 + f], red[1][f]);
        }
    }
}

// ---------------- BatchNorm finalize ----------------

template <int D>
__global__ void k_bnfin(const float* __restrict__ sums, const float* __restrict__ gamma,
                        const float* __restrict__ beta, float* __restrict__ ss) {
    int f = threadIdx.x; // blockDim == D
    float mean = sums[f] * (1.f / N_NODES);
    float var = sums[256 + f] * (1.f / N_NODES) - mean * mean;
    float inv = rsqrtf(var + 1e-5f);
    float sc = gamma[f] * inv;
    ss[f] = sc;
    ss[256 + f] = beta[f] - mean * sc;
}

// ---------------- layer-4 BN apply + classifier ----------------

__global__ __launch_bounds__(256) void k_bnlog(const float* __restrict__ out4, const float* __restrict__ ss,
                                               const float* __restrict__ Wc, const float* __restrict__ bc,
                                               float* __restrict__ bn4, float* __restrict__ logits) {
    int gw = (blockIdx.x * 256 + threadIdx.x) >> 6;
    if (gw >= N_NODES) return;
    int f = threadIdx.x & 63;
    float v = out4[(size_t)gw * 64 + f];
    float bn = v * ss[f] + ss[256 + f];
    bn4[(size_t)gw * 64 + f] = bn;
    float a0 = bn * Wc[2 * f];
    float a1 = bn * Wc[2 * f + 1];
#pragma unroll
    for (int off = 32; off; off >>= 1) {
        a0 += __shfl_down(a0, off, 64);
        a1 += __shfl_down(a1, off, 64);
    }
    if (f == 0) {
        logits[2 * gw] = a0 + bc[0];
        logits[2 * gw + 1] = a1 + bc[1];
    }
}

// ---------------- launch ----------------

extern "C" void kernel_launch(void* const* d_in, const int* in_sizes, int n_in,
                              void* d_out, int out_size, void* d_ws, size_t ws_size,
                              hipStream_t stream) {
    const float* x  = (const float*)d_in[0];
    const int* ei   = (const int*)d_in[1];
    const float* W1 = (const float*)d_in[2];  const float* b1  = (const float*)d_in[3];
    const float* W2 = (const float*)d_in[4];  const float* b2  = (const float*)d_in[5];
    const float* W3 = (const float*)d_in[6];  const float* b3  = (const float*)d_in[7];
    const float* W4 = (const float*)d_in[8];  const float* b4  = (const float*)d_in[9];
    const float* Wc = (const float*)d_in[10]; const float* bc  = (const float*)d_in[11];
    const float* g1 = (const float*)d_in[12]; const float* be1 = (const float*)d_in[13];
    const float* g2 = (const float*)d_in[14]; const float* be2 = (const float*)d_in[15];
    const float* g3 = (const float*)d_in[16]; const float* be3 = (const float*)d_in[17];
    const float* g4 = (const float*)d_in[18]; const float* be4 = (const float*)d_in[19];

    char* wsb = (char*)d_ws;
    size_t off = 0;
    auto alloc = [&](size_t bytes) -> void* {
        void* p = wsb + off;
        off = (off + bytes + 511) & ~(size_t)511;
        return p;
    };
    int* deg     = (int*)alloc((size_t)N_NODES * 4);
    int* basep   = (int*)alloc((size_t)N_NODES * 4);
    float* dinv  = (float*)alloc((size_t)N_NODES * 4);
    float* sdeg  = (float*)alloc((size_t)N_NODES * 4);
    float* svec  = (float*)alloc((size_t)N_NODES * 4);
    int* col     = (int*)alloc((size_t)N_EDGES * 4);
    unsigned* pairs = (unsigned*)alloc((size_t)N_EDGES * 4);
    int* histG   = (int*)alloc((size_t)NB * NBLK * 4);
    int* rowsum  = (int*)alloc((size_t)NB * 4);
    int* rowbase = (int*)alloc((size_t)(NB + 1) * 4);
    float* sums  = (float*)alloc(2048 * 4);  // 4 layer slots of 512
    float* ss    = (float*)alloc(512 * 4);
    unsigned short* Wt1 = (unsigned short*)alloc((size_t)256 * 128 * 2);
    unsigned short* Wt2 = (unsigned short*)alloc((size_t)128 * 256 * 2);
    unsigned short* Wt3 = (unsigned short*)alloc((size_t)256 * 128 * 2);
    unsigned short* Wt4 = (unsigned short*)alloc((size_t)128 * 64 * 2);
    unsigned short* mb = (unsigned short*)alloc((size_t)N_NODES * 128 * 2);
    unsigned short* hb = (unsigned short*)alloc((size_t)N_NODES * 256 * 2);

    float* sums1 = sums, *sums2 = sums + 512, *sums3 = sums + 1024, *sums4 = sums + 1536;

    float* outLogits = (float*)d_out;
    float* out4 = outLogits + (size_t)N_NODES * 2;
    float* bn4  = out4 + (size_t)N_NODES * 64;

    hipMemsetAsync(sums, 0, 2048 * 4, stream);

    // ---- CSR build: partition + bucket sort ----
    k_hist<<<NBLK, 256, 0, stream>>>(ei, histG);
    k_scanrow<<<NB, 128, 0, stream>>>(histG, rowsum);
    k_scanbkt<<<1, 512, 0, stream>>>(rowsum, rowbase);
    k_part<<<NBLK, 256, 0, stream>>>(ei, histG, rowbase, pairs);
    k_bsort<<<NB, 256, 0, stream>>>(pairs, rowbase, col, basep, deg, dinv, sdeg);
    k_svec<<<(N_NODES + 3) / 4, 256, 0, stream>>>(col, basep, deg, dinv, svec);

    k_wconv_all<<<(106496 + 255) / 256, 256, 0, stream>>>(W1, W2, W3, W4, Wt1, Wt2, Wt3, Wt4);

    const int GBM = (N_NODES + 127) / 128; // 782
    const int AB4 = (N_NODES + 63) / 64;   // 1563 blocks, 64 nodes each

    // Layer 1: m1' = dinv*(x @ W1); agg -> q1 = dinv*h1 (bf16) + BN1 stats on h1=q1*sdeg
    k_gemm_bf<128, 2, 2, 0, false, true, false><<<dim3(GBM, 1), 256, 0, stream>>>(
        x, Wt1, nullptr, nullptr, nullptr, dinv, mb, nullptr, 256, 128);
    k_agg4<128, false, false, true, true, true><<<AB4, 256, 0, stream>>>(
        mb, col, basep, deg, dinv, sdeg, b1, hb, sums1);
    k_bnfin<128><<<1, 128, 0, stream>>>(sums1, g1, be1, ss);

    // Layer 2 (commuted): A2 = di*(sum q1 + q1self); h2 = relu((ss*A2 + ss'*svec) @ W2 + b2) + BN2 stats
    k_agg4<128, true, false, false, false, false><<<AB4, 256, 0, stream>>>(
        hb, col, basep, deg, dinv, nullptr, nullptr, mb, nullptr);
    k_gemm_bf<128, 2, 2, 2, true, false, true><<<dim3(GBM, 2), 256, 0, stream>>>(
        mb, Wt2, ss, svec, b2, nullptr, hb, sums2, 128, 256);
    k_bnfin<256><<<1, 256, 0, stream>>>(sums2, g2, be2, ss);

    // Layer 3: m3' = dinv*(affine(h2) @ W3); agg+b3+relu -> h3 + BN3 stats
    k_gemm_bf<128, 2, 2, 1, false, true, false><<<dim3(GBM, 1), 256, 0, stream>>>(
        hb, Wt3, ss, nullptr, nullptr, dinv, mb, nullptr, 256, 128);
    k_agg4<128, false, false, false, true, false><<<AB4, 256, 0, stream>>>(
        mb, col, basep, deg, dinv, nullptr, b3, hb, sums3);
    k_bnfin<128><<<1, 128, 0, stream>>>(sums3, g3, be3, ss);

    // Layer 4: m4' = dinv*(affine(h3) @ W4); agg+b4+relu -> out4 (f32) + BN4 stats; classifier
    k_gemm_bf<64, 4, 1, 1, false, true, false><<<dim3(GBM, 1), 256, 0, stream>>>(
        hb, Wt4, ss, nullptr, nullptr, dinv, mb, nullptr, 128, 64);
    k_agg4<64, false, true, false, true, false><<<AB4, 256, 0, stream>>>(
        mb, col, basep, deg, dinv, nullptr, b4, out4, sums4);
    k_bnfin<64><<<1, 64, 0, stream>>>(sums4, g4, be4, ss);
    k_bnlog<<<(N_NODES * 64 + 255) / 256, 256, 0, stream>>>(out4, ss, Wc, bc, bn4, outLogits);
}